// Round 9
// baseline (894.913 us; speedup 1.0000x reference)
//
#include <hip/hip_runtime.h>
#include <hip/hip_bf16.h>

#define DEV __device__ __forceinline__

typedef __attribute__((ext_vector_type(8))) short short8;
typedef __attribute__((ext_vector_type(4))) float f32x4;

DEV unsigned short f2b(float f) {
  union { float f; unsigned u; } v; v.f = f;
  unsigned r = v.u + 0x7FFFu + ((v.u >> 16) & 1u);  // RNE
  return (unsigned short)(r >> 16);
}
DEV float b2f16(unsigned short b) {
  union { unsigned u; float f; } v; v.u = ((unsigned)b) << 16;
  return v.f;
}

// ---------------- fused weight cast f32 -> bf16 hi/lo arenas ----------------
__global__ void k_castw(const float* __restrict__ s0, const float* __restrict__ s1,
    const float* __restrict__ s2, const float* __restrict__ s3,
    const float* __restrict__ s4, const float* __restrict__ s5,
    const float* __restrict__ s6, const float* __restrict__ s7,
    const float* __restrict__ s8, const float* __restrict__ s9,
    short* __restrict__ dh, short* __restrict__ dl) {
  int idx = blockIdx.x * 256 + threadIdx.x;
  if (idx >= 1096704) return;
  const float* src; int base;
  if      (idx < 165888) { src = s0; base = 0; }
  else if (idx < 175104) { src = s1; base = 165888; }
  else if (idx < 193536) { src = s2; base = 175104; }
  else if (idx < 211968) { src = s3; base = 193536; }
  else if (idx < 285696) { src = s4; base = 211968; }
  else if (idx < 359424) { src = s5; base = 285696; }
  else if (idx < 580608) { src = s6; base = 359424; }
  else if (idx < 654336) { src = s7; base = 580608; }
  else if (idx < 875520) { src = s8; base = 654336; }
  else                   { src = s9; base = 875520; }
  float v = src[idx - base];
  unsigned short h = f2b(v);
  dh[idx] = (short)h;
  dl[idx] = (short)f2b(v - b2f16(h));
}

// ---------------- generic transpose: src[R][C] -> dst[C][R] ----------------
__global__ void k_tr(const float* __restrict__ src, float* __restrict__ dst,
                     int R, int C) {
  int idx = blockIdx.x * 256 + threadIdx.x;
  if (idx >= R * C) return;
  int r = idx / C, c = idx % C;
  dst[(size_t)c * R + r] = src[idx];
}

// ---------------- rope tables: ct/st [784][16] ----------------
__global__ void k_rope(float* ct, float* st) {
  int idx = blockIdx.x * 256 + threadIdx.x;
  if (idx >= 784 * 16) return;
  int n = idx >> 4, j = idx & 15;
  float inv = powf(10000.f, -(float)(2 * j) / 32.f);
  float ang = (float)n * inv;
  ct[idx] = cosf(ang);
  st[idx] = sinf(ang);
}

// ---------------- LN epilogue over D=192: out = (write|add) LN(raw) ----------------
template<int ADD>
__global__ __launch_bounds__(256) void k_ln_epi(const float* __restrict__ raw,
    const float* __restrict__ g, const float* __restrict__ b,
    float* __restrict__ out, int M) {
  int tok = blockIdx.x * 4 + (threadIdx.x >> 6);
  int l = threadIdx.x & 63;
  if (tok >= M) return;
  const float* row = raw + (size_t)tok * 192;
  float v[3];
  float s = 0.f, s2 = 0.f;
#pragma unroll
  for (int e = 0; e < 3; ++e) {
    float x = row[e * 64 + l];
    v[e] = x; s += x; s2 += x * x;
  }
  for (int off = 32; off; off >>= 1) { s += __shfl_xor(s, off); s2 += __shfl_xor(s2, off); }
  float mean = s / 192.f, var = s2 / 192.f - mean * mean;
  float rstd = rsqrtf(var + 1e-5f);
  float* orow = out + (size_t)tok * 192;
#pragma unroll
  for (int e = 0; e < 3; ++e) {
    int i = e * 64 + l;
    float r = (v[e] - mean) * rstd * g[i] + b[i];
    if (ADD) orow[i] += r; else orow[i] = r;
  }
}

// ---------------- MFMA bf16x2 split GEMM: C = (LN?)(A) @ W^T (+bias, epi) ----------------
// 64x64 tile, BK=32, 256 threads = 4 waves (2x2), per-wave 2x2 16x16 frags.
// A f32 -> (hi,lo) bf16 during staging; W pre-split hi/lo arenas.
// acc = ah*bh + ah*bl + al*bh (al*bl dropped, ~eps^2) -> f32-grade accuracy.
// EPI: 0=store 1=gelu+store 2=add-into-C. CONV: im2col. LNP: apply LN(lng,lnb) to A rows.
template<int EPI, int CONV, int LNP>
__global__ __launch_bounds__(256) void k_mgemm(
    const float* __restrict__ A, const short* __restrict__ WH,
    const short* __restrict__ WL, const float* __restrict__ bias,
    const float* __restrict__ lng, const float* __restrict__ lnb,
    float* __restrict__ C, int M, int N, int K) {
  __shared__ short AsH[64][40], AsL[64][40];
  __shared__ short BsH[64][40], BsL[64][40];
  __shared__ float pr[64][4][2];
  __shared__ float rowm[64], rowr[64];
  int t = threadIdx.x;
  int m0 = blockIdx.x * 64, n0 = blockIdx.y * 64;
  int sr = t >> 2, sq = (t & 3) * 8;       // stage: row, k-offset (8 elems/thread)
  int lane = t & 63, w = t >> 6, wm = w >> 1, wn = w & 1;
  int fr = lane & 15, fq = lane >> 4;      // frag row, k-block

  if (LNP) {
    int row = t >> 2, part = t & 3;
    const float* ar = A + (size_t)(m0 + row) * K;
    float s = 0.f, s2 = 0.f;
    for (int k = part; k < K; k += 4) { float v = ar[k]; s += v; s2 += v * v; }
    pr[row][part][0] = s; pr[row][part][1] = s2;
    __syncthreads();
    if (part == 0) {
      float S  = pr[row][0][0] + pr[row][1][0] + pr[row][2][0] + pr[row][3][0];
      float S2 = pr[row][0][1] + pr[row][1][1] + pr[row][2][1] + pr[row][3][1];
      float mean = S / K, var = S2 / K - mean * mean;
      rowm[row] = mean; rowr[row] = rsqrtf(var + 1e-5f);
    }
    __syncthreads();
  }

  f32x4 acc[2][2];
#pragma unroll
  for (int i = 0; i < 2; ++i)
#pragma unroll
    for (int j = 0; j < 2; ++j) acc[i][j] = (f32x4){0.f, 0.f, 0.f, 0.f};

  for (int kt = 0; kt < K; kt += 32) {
    // A tile: 64 rows x 32 k -> hi/lo bf16 (optional LN)
    if (CONV) {
      int m = m0 + sr;
      int b = m / 784, rm = m % 784, ho = rm / 28, wo = rm % 28;
#pragma unroll
      for (int j = 0; j < 8; ++j) {
        int k = kt + sq + j;
        int ci = k / 9, k9 = k % 9;
        int hi = 2 * ho - 1 + k9 / 3, wi = 2 * wo - 1 + k9 % 3;
        float v = 0.f;
        if (hi >= 0 && hi < 56 && wi >= 0 && wi < 56)
          v = A[((size_t)b * 3136 + hi * 56 + wi) * 96 + ci];
        unsigned short h = f2b(v);
        AsH[sr][sq + j] = (short)h;
        AsL[sr][sq + j] = (short)f2b(v - b2f16(h));
      }
    } else {
      const float4 a0 = *(const float4*)&A[(size_t)(m0 + sr) * K + kt + sq];
      const float4 a1 = *(const float4*)&A[(size_t)(m0 + sr) * K + kt + sq + 4];
      float av[8] = {a0.x, a0.y, a0.z, a0.w, a1.x, a1.y, a1.z, a1.w};
#pragma unroll
      for (int j = 0; j < 8; ++j) {
        if (LNP) av[j] = (av[j] - rowm[sr]) * rowr[sr] * lng[kt + sq + j] + lnb[kt + sq + j];
        unsigned short h = f2b(av[j]);
        AsH[sr][sq + j] = (short)h;
        AsL[sr][sq + j] = (short)f2b(av[j] - b2f16(h));
      }
    }
    // B tile: Bs[n][k] = W[n0+n][kt+k] (pre-split bf16, 16B vector copies)
    {
      int n = n0 + sr;
      if (n < N) {
        *(short8*)&BsH[sr][sq] = *(const short8*)&WH[(size_t)n * K + kt + sq];
        *(short8*)&BsL[sr][sq] = *(const short8*)&WL[(size_t)n * K + kt + sq];
      } else {
        short8 z = {0, 0, 0, 0, 0, 0, 0, 0};
        *(short8*)&BsH[sr][sq] = z;
        *(short8*)&BsL[sr][sq] = z;
      }
    }
    __syncthreads();
    short8 ah[2], al[2], bh[2], bl[2];
#pragma unroll
    for (int s = 0; s < 2; ++s) {
      ah[s] = *(const short8*)&AsH[wm * 32 + s * 16 + fr][fq * 8];
      al[s] = *(const short8*)&AsL[wm * 32 + s * 16 + fr][fq * 8];
      bh[s] = *(const short8*)&BsH[wn * 32 + s * 16 + fr][fq * 8];
      bl[s] = *(const short8*)&BsL[wn * 32 + s * 16 + fr][fq * 8];
    }
#pragma unroll
    for (int i = 0; i < 2; ++i)
#pragma unroll
      for (int j = 0; j < 2; ++j) {
        acc[i][j] = __builtin_amdgcn_mfma_f32_16x16x32_bf16(ah[i], bh[j], acc[i][j], 0, 0, 0);
        acc[i][j] = __builtin_amdgcn_mfma_f32_16x16x32_bf16(ah[i], bl[j], acc[i][j], 0, 0, 0);
        acc[i][j] = __builtin_amdgcn_mfma_f32_16x16x32_bf16(al[i], bh[j], acc[i][j], 0, 0, 0);
      }
    __syncthreads();
  }
  // epilogue: C/D layout col = lane&15, row = (lane>>4)*4 + r   [m89]
#pragma unroll
  for (int i = 0; i < 2; ++i) {
#pragma unroll
    for (int j = 0; j < 2; ++j) {
      int n = n0 + wn * 32 + j * 16 + fr;
      if (n >= N) continue;
#pragma unroll
      for (int r = 0; r < 4; ++r) {
        int m = m0 + wm * 32 + i * 16 + fq * 4 + r;
        float v = acc[i][j][r];
        if (bias) v += bias[n];
        if (EPI == 1) v = 0.5f * v * (1.f + erff(v * 0.70710678118654752f));
        if (EPI == 2) C[(size_t)m * N + n] += v;
        else          C[(size_t)m * N + n] = v;
      }
    }
  }
}

// ---------------- pass1: per-input softmax stats; kkT[96][25088] coalesced ----------------
__global__ void k_pass1(const float* __restrict__ kkT, const float* __restrict__ q,
    const float* __restrict__ rpb, const float* __restrict__ tau,
    float* __restrict__ M, float* __restrict__ Z) {
  int id = blockIdx.x * 256 + threadIdx.x;
  if (id >= 8 * 3136) return;
  int b = id / 3136, n = id % 3136;
  int r = n / 56, c = n % 56, r0 = r >> 1, c0 = c >> 1;
  int oi[9];
#pragma unroll
  for (int kki = 0; kki < 9; ++kki) {
    int dr = kki / 3 - 1, dc = kki % 3 - 1;
    int rr = min(max(r0 + dr, 0), 27), cc = min(max(c0 + dc, 0), 27);
    oi[kki] = rr * 28 + cc;
  }
  float scale = expf(tau[0]);
  float lg[9]; bool keep[9];
  float mx = -1e30f;
#pragma unroll
  for (int kki = 0; kki < 9; ++kki) {
    bool kp = true;
#pragma unroll
    for (int k2 = kki + 1; k2 < 9; ++k2) if (oi[k2] == oi[kki]) kp = false;
    keep[kki] = kp;
    if (kp) {
      const float* qr = q + ((size_t)b * 784 + oi[kki]) * 96;
      float d = 0.f;
      for (int i = 0; i < 96; ++i) d += kkT[(size_t)i * 25088 + id] * qr[i];
      lg[kki] = d * scale + rpb[kki];
      mx = fmaxf(mx, lg[kki]);
    } else lg[kki] = -1e30f;
  }
  float z = 0.f;
#pragma unroll
  for (int kki = 0; kki < 9; ++kki) if (keep[kki]) z += expf(lg[kki] - mx);
  M[id] = mx; Z[id] = z;
}

// ---------------- pass2: gather contributors, upd, /denom, LN, residual ----------------
__global__ __launch_bounds__(192) void k_pass2(const float* __restrict__ kk,
    const float* __restrict__ q, const float* __restrict__ vv,
    const float* __restrict__ M, const float* __restrict__ Z,
    const float* __restrict__ rpb, const float* __restrict__ tau,
    const float* __restrict__ g, const float* __restrict__ bb, float* __restrict__ xout) {
  int blk = blockIdx.x, b = blk / 784, m = blk % 784;
  int r2 = m / 28, c2 = m % 28;
  int r0lo = (r2 == 0) ? 0 : r2 - 1, r0hi = (r2 == 27) ? 27 : r2 + 1;
  int c0lo = (c2 == 0) ? 0 : c2 - 1, c0hi = (c2 == 27) ? 27 : c2 + 1;
  int nrow = 2 * (r0hi - r0lo + 1), ncol = 2 * (c0hi - c0lo + 1);
  int cnt = nrow * ncol;  // <= 36
  __shared__ float qm[96], p[36];
  __shared__ int nlist[36];
  __shared__ float2 red[192];
  int t = threadIdx.x;
  if (t < 96) qm[t] = q[(size_t)blk * 96 + t];
  __syncthreads();
  if (t < cnt) {
    int rr = 2 * r0lo + t / ncol, cc = 2 * c0lo + t % ncol;
    int n = rr * 56 + cc, rr0 = rr >> 1, cc0 = cc >> 1;
    int kkf = 0;
#pragma unroll
    for (int kki = 0; kki < 9; ++kki) {
      int dr = kki / 3 - 1, dc = kki % 3 - 1;
      int ra = min(max(rr0 + dr, 0), 27), ca = min(max(cc0 + dc, 0), 27);
      if (ra == r2 && ca == c2) kkf = kki;  // last-kk-wins (matches numpy overwrite)
    }
    const float* krow = kk + ((size_t)b * 3136 + n) * 96;
    float d = 0.f;
    for (int i = 0; i < 96; ++i) d += krow[i] * qm[i];
    float scale = expf(tau[0]);
    float lg = d * scale + rpb[kkf];
    size_t idn = (size_t)b * 3136 + n;
    p[t] = expf(lg - M[idn]) / Z[idn];
    nlist[t] = n;
  }
  __syncthreads();
  float denom = 0.f;
  for (int jn = 0; jn < cnt; ++jn) denom += p[jn];
  float acc = 0.f;
  for (int jn = 0; jn < cnt; ++jn)
    acc += p[jn] * vv[((size_t)b * 3136 + nlist[jn]) * 192 + t];
  float upd = acc / (denom + 1e-8f);
  red[t] = make_float2(upd, upd * upd);
  __syncthreads();
  for (int s = 128; s > 0; s >>= 1) {
    if (t < s && t + s < 192) { red[t].x += red[t + s].x; red[t].y += red[t + s].y; }
    __syncthreads();
  }
  float mean = red[0].x / 192.f, var = red[0].y / 192.f - mean * mean;
  float rstd = rsqrtf(var + 1e-5f);
  xout[(size_t)blk * 192 + t] += (upd - mean) * rstd * g[t] + bb[t];
}

// ---------------- rope + scatter: RAW[6272][576] -> q3/k3/v3 [b][6][784][32] ----------------
__global__ void k_rope_scatter(const float* __restrict__ raw,
    const float* __restrict__ ct, const float* __restrict__ st,
    float* __restrict__ q3, float* __restrict__ k3, float* __restrict__ v3) {
  int idx = blockIdx.x * 256 + threadIdx.x;
  if (idx >= 8 * 784 * 576) return;
  int tok = idx / 576, d5 = idx % 576;
  int b = tok / 784, m = tok % 784;
  int sec = d5 / 192, d = d5 % 192, h = d / 32, dh = d % 32;
  float me = raw[idx], val;
  if (sec < 2) {
    float pa = raw[(size_t)tok * 576 + sec * 192 + (d ^ 1)];
    int j = dh >> 1;
    float cc = ct[m * 16 + j], ss = st[m * 16 + j];
    val = (dh & 1) ? (me * cc + pa * ss) : (me * cc - pa * ss);
  } else val = me;
  float* dst = (sec == 0) ? q3 : ((sec == 1) ? k3 : v3);
  dst[(((size_t)b * 6 + h) * 784 + m) * 32 + dh] = val;
}

// ---------------- neighborhood attention 7x7: LDS band staging ----------------
// one block per (b,h,row i): grid 1344 = 8*168, XCD-swizzled. 256 threads = 4 waves.
// K/V rows ib..ib+6 are contiguous in memory -> coalesced float4 staging.
// LDS layout [7][28][33] (pad 33 -> QK/PV reads ~2-way conflicts, free).
__global__ __launch_bounds__(256) void k_attn(const float* __restrict__ q3,
    const float* __restrict__ k3, const float* __restrict__ v3, float* __restrict__ ob) {
  __shared__ float Kl[6468], Vl[6468], Ql[896];
  int bid = blockIdx.x;
  int swz = (bid & 7) * 168 + (bid >> 3);   // bijective on [0,1344)
  int b = swz / 168, rem = swz % 168, h = rem / 28, i = rem % 28;
  int ib = min(max(i, 3), 24) - 3;
  size_t base = (size_t)(b * 6 + h) * 784 * 32;
  const float* Ksrc = k3 + base + (size_t)ib * 28 * 32;   // 6272 contiguous floats
  const float* Vsrc = v3 + base + (size_t)ib * 28 * 32;
  const float* Qsrc = q3 + base + (size_t)i * 28 * 32;    // 896 contiguous floats
  int t = threadIdx.x;
  for (int idx = t; idx < 1568; idx += 256) {
    float4 k4 = *(const float4*)&Ksrc[idx * 4];
    float4 v4 = *(const float4*)&Vsrc[idx * 4];
    int d = (idx & 7) * 4, rc = idx >> 3;
    int lo = rc * 33 + d;
    Kl[lo] = k4.x; Kl[lo + 1] = k4.y; Kl[lo + 2] = k4.z; Kl[lo + 3] = k4.w;
    Vl[lo] = v4.x; Vl[lo + 1] = v4.y; Vl[lo + 2] = v4.z; Vl[lo + 3] = v4.w;
  }
  for (int idx = t; idx < 896; idx += 256) Ql[idx] = Qsrc[idx];
  __syncthreads();
  int w = t >> 6, l = t & 63;
  for (int jj = 0; jj < 7; ++jj) {
    int j = w * 7 + jj;
    int jb = min(max(j, 3), 24) - 3;
    float logit = -1e30f;
    if (l < 49) {
      int rc = (l / 7) * 28 + jb + (l % 7);
      const float* kr = &Kl[rc * 33];
      const float* qr = &Ql[j * 32];
      float a = 0.f;
#pragma unroll
      for (int d = 0; d < 32; ++d) a += kr[d] * qr[d];
      logit = a * 0.17677669529663687f;  // 32^-0.5
    }
    float mx = logit;
    for (int off = 32; off; off >>= 1) mx = fmaxf(mx, __shfl_xor(mx, off));
    float p = (l < 49) ? expf(logit - mx) : 0.f;
    float sum = p;
    for (int off = 32; off; off >>= 1) sum += __shfl_xor(sum, off);
    int d = l & 31;
    float acc = 0.f;
    for (int kki = 0; kki < 49; ++kki) {
      float pk = __shfl(p, kki);
      int rck = (kki / 7) * 28 + jb + (kki % 7);
      acc += pk * Vl[rck * 33 + d];
    }
    if (l < 32) {
      int m = i * 28 + j;
      ob[(((size_t)b * 784 + m) * 6 + h) * 32 + l] = acc / sum;
    }
  }
}

extern "C" void kernel_launch(void* const* d_in, const int* in_sizes, int n_in,
                              void* d_out, int out_size, void* d_ws, size_t ws_size,
                              hipStream_t stream) {
  (void)in_sizes; (void)n_in; (void)out_size; (void)ws_size;
  const float* x        = (const float*)d_in[0];
  const float* convw    = (const float*)d_in[1];
  const float* qw       = (const float*)d_in[2];
  const float* kw       = (const float*)d_in[3];
  const float* vw       = (const float*)d_in[4];
  const float* ln_in_g  = (const float*)d_in[5];
  const float* ln_in_b  = (const float*)d_in[6];
  const float* ln_out_g = (const float*)d_in[7];
  const float* ln_out_b = (const float*)d_in[8];
  const float* ln_at_g  = (const float*)d_in[9];
  const float* ln_at_b  = (const float*)d_in[10];
  const float* ln_ml_g  = (const float*)d_in[11];
  const float* ln_ml_b  = (const float*)d_in[12];
  const float* gw1      = (const float*)d_in[13];
  const float* gb1      = (const float*)d_in[14];
  const float* gw2      = (const float*)d_in[15];
  const float* gb2      = (const float*)d_in[16];
  const float* tau      = (const float*)d_in[17];
  const float* rpb      = (const float*)d_in[18];
  const float* bln1g    = (const float*)d_in[19];
  const float* bln1b    = (const float*)d_in[20];
  const float* bln2g    = (const float*)d_in[21];
  const float* bln2b    = (const float*)d_in[22];
  const float* bqkvw    = (const float*)d_in[23];
  const float* bprojw   = (const float*)d_in[24];
  const float* bprojb   = (const float*)d_in[25];
  const float* bmw1     = (const float*)d_in[26];
  const float* bmb1     = (const float*)d_in[27];
  const float* bmw2     = (const float*)d_in[28];
  const float* bmb2     = (const float*)d_in[29];

  float* XOUT = (float*)d_out;  // residual stream lives in d_out (f32, 8*784*192)

  float* W = (float*)d_ws;
  size_t off = 0;
  float* KbT   = W + off; off += (size_t)96 * 25088;
  float* Kb    = W + off; off += (size_t)25088 * 96;
  float* Vb    = W + off; off += (size_t)25088 * 192;
  float* Qb    = W + off; off += (size_t)6272 * 96;
  float* Mb    = W + off; off += (size_t)25088;
  float* Zb    = W + off; off += (size_t)25088;
  float* H1    = W + off; off += (size_t)6272 * 576;   // also QKVRAW
  float* T2    = W + off; off += (size_t)6272 * 192;   // also CRAW
  float* CT    = W + off; off += (size_t)784 * 16;
  float* ST    = W + off; off += (size_t)784 * 16;
  short* WBH   = (short*)(W + off); off += (size_t)548352 + 16;  // hi arena
  short* WBL   = (short*)(W + off); off += (size_t)548352 + 16;  // lo arena
  // bf16 weight arena offsets (elements)
  const size_t O_c = 0, O_k = 165888, O_v = 175104, O_q = 193536,
               O_g1 = 211968, O_g2 = 285696, O_qkv = 359424, O_p = 580608,
               O_m1 = 654336, O_m2 = 875520;
  // aliases
  float* CRAW = T2;
  float* QKVRAW = H1;
  float* Q3 = Kb;                       // block phase: Kb/Vb/KbT dead
  float* K3 = KbT;
  float* V3 = Vb;
  float* OB = Vb + (size_t)1204224;

  k_castw<<<4284, 256, 0, stream>>>(convw, kw, vw, qw, gw1, gw2, bqkvw, bprojw,
                                    bmw1, bmw2, WBH, WBL);
  k_rope<<<49, 256, 0, stream>>>(CT, ST);

  // conv (implicit GEMM, K=864) + LN
  k_mgemm<0, 1, 0><<<dim3(98, 3), 256, 0, stream>>>(x, WBH + O_c, WBL + O_c, nullptr,
      nullptr, nullptr, CRAW, 6272, 192, 864);
  k_ln_epi<0><<<1568, 256, 0, stream>>>(CRAW, ln_out_g, ln_out_b, XOUT, 6272);

  // k,v projections with fused LN(x; ln_in)
  k_mgemm<0, 0, 1><<<dim3(392, 2), 256, 0, stream>>>(x, WBH + O_k, WBL + O_k, nullptr,
      ln_in_g, ln_in_b, Kb, 25088, 96, 96);
  k_mgemm<0, 0, 1><<<dim3(392, 3), 256, 0, stream>>>(x, WBH + O_v, WBL + O_v, nullptr,
      ln_in_g, ln_in_b, Vb, 25088, 192, 96);
  k_tr<<<(25088 * 96 + 255) / 256, 256, 0, stream>>>(Kb, KbT, 25088, 96);

  for (int it = 0; it < 3; ++it) {
    // q = LN(XOUT; ln_out) @ qw^T (LN fused)
    k_mgemm<0, 0, 1><<<dim3(98, 2), 256, 0, stream>>>(XOUT, WBH + O_q, WBL + O_q, nullptr,
        ln_out_g, ln_out_b, Qb, 6272, 96, 192);
    k_pass1<<<98, 256, 0, stream>>>(KbT, Qb, rpb, tau, Mb, Zb);
    k_pass2<<<6272, 192, 0, stream>>>(Kb, Qb, Vb, Mb, Zb, rpb, tau, ln_at_g, ln_at_b, XOUT);
    k_mgemm<1, 0, 0><<<dim3(98, 6), 256, 0, stream>>>(XOUT, WBH + O_g1, WBL + O_g1, gb1,
        nullptr, nullptr, H1, 6272, 384, 192);
    k_mgemm<0, 0, 0><<<dim3(98, 3), 256, 0, stream>>>(H1, WBH + O_g2, WBL + O_g2, gb2,
        nullptr, nullptr, T2, 6272, 192, 384);
    k_ln_epi<1><<<1568, 256, 0, stream>>>(T2, ln_ml_g, ln_ml_b, XOUT, 6272);
  }

  for (int i = 0; i < 2; ++i) {
    // qkv = LN(XOUT; bln1) @ qkvw^T (LN fused)
    k_mgemm<0, 0, 1><<<dim3(98, 9), 256, 0, stream>>>(XOUT, WBH + O_qkv + (size_t)i * 110592,
        WBL + O_qkv + (size_t)i * 110592, nullptr,
        bln1g + (size_t)i * 192, bln1b + (size_t)i * 192, QKVRAW, 6272, 576, 192);
    k_rope_scatter<<<(8 * 784 * 576 + 255) / 256, 256, 0, stream>>>(QKVRAW, CT, ST, Q3, K3, V3);
    k_attn<<<1344, 256, 0, stream>>>(Q3, K3, V3, OB);
    k_mgemm<2, 0, 0><<<dim3(98, 3), 256, 0, stream>>>(OB, WBH + O_p + (size_t)i * 36864,
        WBL + O_p + (size_t)i * 36864, bprojb + (size_t)i * 192,
        nullptr, nullptr, XOUT, 6272, 192, 192);
    // h = gelu(LN(XOUT; bln2) @ mw1^T + b1) (LN fused)
    k_mgemm<1, 0, 1><<<dim3(98, 9), 256, 0, stream>>>(XOUT, WBH + O_m1 + (size_t)i * 110592,
        WBL + O_m1 + (size_t)i * 110592, bmb1 + (size_t)i * 576,
        bln2g + (size_t)i * 192, bln2b + (size_t)i * 192, H1, 6272, 576, 192);
    k_mgemm<2, 0, 0><<<dim3(98, 3), 256, 0, stream>>>(H1, WBH + O_m2 + (size_t)i * 110592,
        WBL + O_m2 + (size_t)i * 110592, bmb2 + (size_t)i * 192,
        nullptr, nullptr, XOUT, 6272, 192, 576);
  }
}

// Round 10
// 810.893 us; speedup vs baseline: 1.1036x; 1.1036x over previous
//
#include <hip/hip_runtime.h>
#include <hip/hip_bf16.h>

#define DEV __device__ __forceinline__

typedef __attribute__((ext_vector_type(8))) short short8;
typedef __attribute__((ext_vector_type(4))) float f32x4;

DEV unsigned short f2b(float f) {
  union { float f; unsigned u; } v; v.f = f;
  unsigned r = v.u + 0x7FFFu + ((v.u >> 16) & 1u);  // RNE
  return (unsigned short)(r >> 16);
}
DEV float b2f16(unsigned short b) {
  union { unsigned u; float f; } v; v.u = ((unsigned)b) << 16;
  return v.f;
}

// ---------------- fused weight cast f32 -> bf16 hi/lo arenas ----------------
__global__ void k_castw(const float* __restrict__ s0, const float* __restrict__ s1,
    const float* __restrict__ s2, const float* __restrict__ s3,
    const float* __restrict__ s4, const float* __restrict__ s5,
    const float* __restrict__ s6, const float* __restrict__ s7,
    const float* __restrict__ s8, const float* __restrict__ s9,
    short* __restrict__ dh, short* __restrict__ dl) {
  int idx = blockIdx.x * 256 + threadIdx.x;
  if (idx >= 1096704) return;
  const float* src; int base;
  if      (idx < 165888) { src = s0; base = 0; }
  else if (idx < 175104) { src = s1; base = 165888; }
  else if (idx < 193536) { src = s2; base = 175104; }
  else if (idx < 211968) { src = s3; base = 193536; }
  else if (idx < 285696) { src = s4; base = 211968; }
  else if (idx < 359424) { src = s5; base = 285696; }
  else if (idx < 580608) { src = s6; base = 359424; }
  else if (idx < 654336) { src = s7; base = 580608; }
  else if (idx < 875520) { src = s8; base = 654336; }
  else                   { src = s9; base = 875520; }
  float v = src[idx - base];
  unsigned short h = f2b(v);
  dh[idx] = (short)h;
  dl[idx] = (short)f2b(v - b2f16(h));
}

// ---------------- generic transpose: src[R][C] -> dst[C][R] ----------------
__global__ void k_tr(const float* __restrict__ src, float* __restrict__ dst,
                     int R, int C) {
  int idx = blockIdx.x * 256 + threadIdx.x;
  if (idx >= R * C) return;
  int r = idx / C, c = idx % C;
  dst[(size_t)c * R + r] = src[idx];
}

// ---------------- rope tables: ct/st [784][16] ----------------
__global__ void k_rope(float* ct, float* st) {
  int idx = blockIdx.x * 256 + threadIdx.x;
  if (idx >= 784 * 16) return;
  int n = idx >> 4, j = idx & 15;
  float inv = powf(10000.f, -(float)(2 * j) / 32.f);
  float ang = (float)n * inv;
  ct[idx] = cosf(ang);
  st[idx] = sinf(ang);
}

// ---------------- LN over last dim D, wave per token, 4 tokens/block ----------------
template<int D>
__global__ __launch_bounds__(256) void k_ln(const float* __restrict__ in,
    const float* __restrict__ g, const float* __restrict__ b,
    float* __restrict__ out, int M) {
  int tok = blockIdx.x * 4 + (threadIdx.x >> 6);
  int l = threadIdx.x & 63;
  if (tok >= M) return;  // wave-uniform
  const float* row = in + (size_t)tok * D;
  constexpr int E = (D + 63) / 64;
  float v[E];
  float s = 0.f, s2 = 0.f;
#pragma unroll
  for (int e = 0; e < E; ++e) {
    int i = e * 64 + l;
    float x = (i < D) ? row[i] : 0.f;
    v[e] = x; s += x; s2 += x * x;
  }
  for (int off = 32; off; off >>= 1) { s += __shfl_xor(s, off); s2 += __shfl_xor(s2, off); }
  float mean = s / D, var = s2 / D - mean * mean;
  float rstd = rsqrtf(var + 1e-5f);
  float* orow = out + (size_t)tok * D;
#pragma unroll
  for (int e = 0; e < E; ++e) {
    int i = e * 64 + l;
    if (i < D) orow[i] = (v[e] - mean) * rstd * g[i] + b[i];
  }
}

// ---------------- LN epilogue over D=192: out = (write|add) LN(raw) ----------------
template<int ADD>
__global__ __launch_bounds__(256) void k_ln_epi(const float* __restrict__ raw,
    const float* __restrict__ g, const float* __restrict__ b,
    float* __restrict__ out, int M) {
  int tok = blockIdx.x * 4 + (threadIdx.x >> 6);
  int l = threadIdx.x & 63;
  if (tok >= M) return;
  const float* row = raw + (size_t)tok * 192;
  float v[3];
  float s = 0.f, s2 = 0.f;
#pragma unroll
  for (int e = 0; e < 3; ++e) {
    float x = row[e * 64 + l];
    v[e] = x; s += x; s2 += x * x;
  }
  for (int off = 32; off; off >>= 1) { s += __shfl_xor(s, off); s2 += __shfl_xor(s2, off); }
  float mean = s / 192.f, var = s2 / 192.f - mean * mean;
  float rstd = rsqrtf(var + 1e-5f);
  float* orow = out + (size_t)tok * 192;
#pragma unroll
  for (int e = 0; e < 3; ++e) {
    int i = e * 64 + l;
    float r = (v[e] - mean) * rstd * g[i] + b[i];
    if (ADD) orow[i] += r; else orow[i] = r;
  }
}

// ---------------- MFMA bf16x2 split GEMM: C = A @ W^T, f32-grade accuracy ----------------
// 64x64 tile, BK=32, 256 threads = 4 waves (2x2), per-wave 2x2 16x16 frags.
// acc = ah*bh + ah*bl + al*bh (al*bl dropped, ~eps^2).
// EPI: 0 = store, 1 = gelu+store, 2 = add-into-C.  CONV: im2col from x[b][56][56][96].
template<int EPI, int CONV>
__global__ __launch_bounds__(256) void k_mgemm(
    const float* __restrict__ A, const short* __restrict__ WH,
    const short* __restrict__ WL, const float* __restrict__ bias,
    float* __restrict__ C, int M, int N, int K) {
  __shared__ short AsH[64][40], AsL[64][40];
  __shared__ short BsH[64][40], BsL[64][40];
  int t = threadIdx.x;
  int m0 = blockIdx.x * 64, n0 = blockIdx.y * 64;
  int sr = t >> 2, sq = (t & 3) * 8;       // stage: row, k-offset (8 elems/thread)
  int lane = t & 63, w = t >> 6, wm = w >> 1, wn = w & 1;
  int fr = lane & 15, fq = lane >> 4;      // frag row, k-block
  f32x4 acc[2][2];
#pragma unroll
  for (int i = 0; i < 2; ++i)
#pragma unroll
    for (int j = 0; j < 2; ++j) acc[i][j] = (f32x4){0.f, 0.f, 0.f, 0.f};

  for (int kt = 0; kt < K; kt += 32) {
    if (CONV) {
      int m = m0 + sr;
      int b = m / 784, rm = m % 784, ho = rm / 28, wo = rm % 28;
#pragma unroll
      for (int j = 0; j < 8; ++j) {
        int k = kt + sq + j;
        int ci = k / 9, k9 = k % 9;
        int hi = 2 * ho - 1 + k9 / 3, wi = 2 * wo - 1 + k9 % 3;
        float v = 0.f;
        if (hi >= 0 && hi < 56 && wi >= 0 && wi < 56)
          v = A[((size_t)b * 3136 + hi * 56 + wi) * 96 + ci];
        unsigned short h = f2b(v);
        AsH[sr][sq + j] = (short)h;
        AsL[sr][sq + j] = (short)f2b(v - b2f16(h));
      }
    } else {
      const float4 a0 = *(const float4*)&A[(size_t)(m0 + sr) * K + kt + sq];
      const float4 a1 = *(const float4*)&A[(size_t)(m0 + sr) * K + kt + sq + 4];
      float av[8] = {a0.x, a0.y, a0.z, a0.w, a1.x, a1.y, a1.z, a1.w};
#pragma unroll
      for (int j = 0; j < 8; ++j) {
        unsigned short h = f2b(av[j]);
        AsH[sr][sq + j] = (short)h;
        AsL[sr][sq + j] = (short)f2b(av[j] - b2f16(h));
      }
    }
    {
      int n = n0 + sr;
      if (n < N) {
        *(short8*)&BsH[sr][sq] = *(const short8*)&WH[(size_t)n * K + kt + sq];
        *(short8*)&BsL[sr][sq] = *(const short8*)&WL[(size_t)n * K + kt + sq];
      } else {
        short8 z = {0, 0, 0, 0, 0, 0, 0, 0};
        *(short8*)&BsH[sr][sq] = z;
        *(short8*)&BsL[sr][sq] = z;
      }
    }
    __syncthreads();
    short8 ah[2], al[2], bh[2], bl[2];
#pragma unroll
    for (int s = 0; s < 2; ++s) {
      ah[s] = *(const short8*)&AsH[wm * 32 + s * 16 + fr][fq * 8];
      al[s] = *(const short8*)&AsL[wm * 32 + s * 16 + fr][fq * 8];
      bh[s] = *(const short8*)&BsH[wn * 32 + s * 16 + fr][fq * 8];
      bl[s] = *(const short8*)&BsL[wn * 32 + s * 16 + fr][fq * 8];
    }
#pragma unroll
    for (int i = 0; i < 2; ++i)
#pragma unroll
      for (int j = 0; j < 2; ++j) {
        acc[i][j] = __builtin_amdgcn_mfma_f32_16x16x32_bf16(ah[i], bh[j], acc[i][j], 0, 0, 0);
        acc[i][j] = __builtin_amdgcn_mfma_f32_16x16x32_bf16(ah[i], bl[j], acc[i][j], 0, 0, 0);
        acc[i][j] = __builtin_amdgcn_mfma_f32_16x16x32_bf16(al[i], bh[j], acc[i][j], 0, 0, 0);
      }
    __syncthreads();
  }
  // epilogue: C/D layout col = lane&15, row = (lane>>4)*4 + r   [m89]
#pragma unroll
  for (int i = 0; i < 2; ++i) {
#pragma unroll
    for (int j = 0; j < 2; ++j) {
      int n = n0 + wn * 32 + j * 16 + fr;
      if (n >= N) continue;
#pragma unroll
      for (int r = 0; r < 4; ++r) {
        int m = m0 + wm * 32 + i * 16 + fq * 4 + r;
        float v = acc[i][j][r];
        if (bias) v += bias[n];
        if (EPI == 1) v = 0.5f * v * (1.f + erff(v * 0.70710678118654752f));
        if (EPI == 2) C[(size_t)m * N + n] += v;
        else          C[(size_t)m * N + n] = v;
      }
    }
  }
}

// ---------------- pass1: per-input softmax stats; kkT[96][25088] coalesced ----------------
__global__ void k_pass1(const float* __restrict__ kkT, const float* __restrict__ q,
    const float* __restrict__ rpb, const float* __restrict__ tau,
    float* __restrict__ M, float* __restrict__ Z) {
  int id = blockIdx.x * 256 + threadIdx.x;
  if (id >= 8 * 3136) return;
  int b = id / 3136, n = id % 3136;
  int r = n / 56, c = n % 56, r0 = r >> 1, c0 = c >> 1;
  int oi[9];
#pragma unroll
  for (int kki = 0; kki < 9; ++kki) {
    int dr = kki / 3 - 1, dc = kki % 3 - 1;
    int rr = min(max(r0 + dr, 0), 27), cc = min(max(c0 + dc, 0), 27);
    oi[kki] = rr * 28 + cc;
  }
  float scale = expf(tau[0]);
  float lg[9]; bool keep[9];
  float mx = -1e30f;
#pragma unroll
  for (int kki = 0; kki < 9; ++kki) {
    bool kp = true;
#pragma unroll
    for (int k2 = kki + 1; k2 < 9; ++k2) if (oi[k2] == oi[kki]) kp = false;
    keep[kki] = kp;
    if (kp) {
      const float* qr = q + ((size_t)b * 784 + oi[kki]) * 96;
      float d = 0.f;
      for (int i = 0; i < 96; ++i) d += kkT[(size_t)i * 25088 + id] * qr[i];
      lg[kki] = d * scale + rpb[kki];
      mx = fmaxf(mx, lg[kki]);
    } else lg[kki] = -1e30f;
  }
  float z = 0.f;
#pragma unroll
  for (int kki = 0; kki < 9; ++kki) if (keep[kki]) z += expf(lg[kki] - mx);
  M[id] = mx; Z[id] = z;
}

// ---------------- pass2: gather contributors, upd, /denom, LN, residual ----------------
__global__ __launch_bounds__(192) void k_pass2(const float* __restrict__ kk,
    const float* __restrict__ q, const float* __restrict__ vv,
    const float* __restrict__ M, const float* __restrict__ Z,
    const float* __restrict__ rpb, const float* __restrict__ tau,
    const float* __restrict__ g, const float* __restrict__ bb, float* __restrict__ xout) {
  int blk = blockIdx.x, b = blk / 784, m = blk % 784;
  int r2 = m / 28, c2 = m % 28;
  int r0lo = (r2 == 0) ? 0 : r2 - 1, r0hi = (r2 == 27) ? 27 : r2 + 1;
  int c0lo = (c2 == 0) ? 0 : c2 - 1, c0hi = (c2 == 27) ? 27 : c2 + 1;
  int nrow = 2 * (r0hi - r0lo + 1), ncol = 2 * (c0hi - c0lo + 1);
  int cnt = nrow * ncol;  // <= 36
  __shared__ float qm[96], p[36];
  __shared__ int nlist[36];
  __shared__ float2 red[192];
  int t = threadIdx.x;
  if (t < 96) qm[t] = q[(size_t)blk * 96 + t];
  __syncthreads();
  if (t < cnt) {
    int rr = 2 * r0lo + t / ncol, cc = 2 * c0lo + t % ncol;
    int n = rr * 56 + cc, rr0 = rr >> 1, cc0 = cc >> 1;
    int kkf = 0;
#pragma unroll
    for (int kki = 0; kki < 9; ++kki) {
      int dr = kki / 3 - 1, dc = kki % 3 - 1;
      int ra = min(max(rr0 + dr, 0), 27), ca = min(max(cc0 + dc, 0), 27);
      if (ra == r2 && ca == c2) kkf = kki;  // last-kk-wins (matches numpy overwrite)
    }
    const float* krow = kk + ((size_t)b * 3136 + n) * 96;
    float d = 0.f;
    for (int i = 0; i < 96; ++i) d += krow[i] * qm[i];
    float scale = expf(tau[0]);
    float lg = d * scale + rpb[kkf];
    size_t idn = (size_t)b * 3136 + n;
    p[t] = expf(lg - M[idn]) / Z[idn];
    nlist[t] = n;
  }
  __syncthreads();
  float denom = 0.f;
  for (int jn = 0; jn < cnt; ++jn) denom += p[jn];
  float acc = 0.f;
  for (int jn = 0; jn < cnt; ++jn)
    acc += p[jn] * vv[((size_t)b * 3136 + nlist[jn]) * 192 + t];
  float upd = acc / (denom + 1e-8f);
  red[t] = make_float2(upd, upd * upd);
  __syncthreads();
  for (int s = 128; s > 0; s >>= 1) {
    if (t < s && t + s < 192) { red[t].x += red[t + s].x; red[t].y += red[t + s].y; }
    __syncthreads();
  }
  float mean = red[0].x / 192.f, var = red[0].y / 192.f - mean * mean;
  float rstd = rsqrtf(var + 1e-5f);
  xout[(size_t)blk * 192 + t] += (upd - mean) * rstd * g[t] + bb[t];
}

// ---------------- rope + scatter: RAW[6272][576] -> q3/k3/v3 [b][6][784][32] ----------------
__global__ void k_rope_scatter(const float* __restrict__ raw,
    const float* __restrict__ ct, const float* __restrict__ st,
    float* __restrict__ q3, float* __restrict__ k3, float* __restrict__ v3) {
  int idx = blockIdx.x * 256 + threadIdx.x;
  if (idx >= 8 * 784 * 576) return;
  int tok = idx / 576, d5 = idx % 576;
  int b = tok / 784, m = tok % 784;
  int sec = d5 / 192, d = d5 % 192, h = d / 32, dh = d % 32;
  float me = raw[idx], val;
  if (sec < 2) {
    float pa = raw[(size_t)tok * 576 + sec * 192 + (d ^ 1)];
    int j = dh >> 1;
    float cc = ct[m * 16 + j], ss = st[m * 16 + j];
    val = (dh & 1) ? (me * cc + pa * ss) : (me * cc - pa * ss);
  } else val = me;
  float* dst = (sec == 0) ? q3 : ((sec == 1) ? k3 : v3);
  dst[(((size_t)b * 6 + h) * 784 + m) * 32 + dh] = val;
}

// ---------------- neighborhood attention 7x7: wide, vectorized, split-PV ----------------
// one wave per (b,h,pixel); grid 9408 x 256 (4 waves/block), XCD swizzle (9408 = 8*1176).
// QK: Q row preloaded to 8 float4 regs; K rows read as float4 (4x fewer VMEM ops).
// PV: lanes 0-31 accumulate neighbors 0-24, lanes 32-63 neighbors 25-48; one
// shfl_xor(32) combines. All shuffles wave-uniform-active.
__global__ __launch_bounds__(256) void k_attn(const float* __restrict__ q3,
    const float* __restrict__ k3, const float* __restrict__ v3, float* __restrict__ ob) {
  int bid = blockIdx.x;
  int swz = (bid & 7) * 1176 + (bid >> 3);  // bijective on [0,9408)
  int unit = swz * 4 + (threadIdx.x >> 6);
  int l = threadIdx.x & 63;
  int b = unit / (6 * 784), rem = unit % (6 * 784), h = rem / 784, m = rem % 784;
  int i = m / 28, j = m % 28;
  int ib = min(max(i, 3), 24) - 3, jb = min(max(j, 3), 24) - 3;
  size_t base = (size_t)(b * 6 + h) * 784 * 32;
  const float4* q4 = (const float4*)(q3 + base + (size_t)m * 32);
  float4 qv[8];
#pragma unroll
  for (int e = 0; e < 8; ++e) qv[e] = q4[e];  // wave-uniform, L1/L2-hit
  float logit = -1e30f;
  if (l < 49) {
    int nk = (ib + l / 7) * 28 + (jb + l % 7);
    const float4* k4 = (const float4*)(k3 + base + (size_t)nk * 32);
    float a = 0.f;
#pragma unroll
    for (int e = 0; e < 8; ++e) {
      float4 kv = k4[e];
      a += qv[e].x * kv.x + qv[e].y * kv.y + qv[e].z * kv.z + qv[e].w * kv.w;
    }
    logit = a * 0.17677669529663687f;  // 32^-0.5
  }
  float mx = logit;
  for (int off = 32; off; off >>= 1) mx = fmaxf(mx, __shfl_xor(mx, off));
  float p = (l < 49) ? expf(logit - mx) : 0.f;
  float sum = p;
  for (int off = 32; off; off >>= 1) sum += __shfl_xor(sum, off);
  // split PV: half 0 -> kki 0..24, half 1 -> kki 25..48
  int half = l >> 5, d = l & 31;
  int kbeg = half ? 25 : 0, kend = half ? 49 : 25;
  float acc = 0.f;
  for (int kki = kbeg; kki < kend; ++kki) {
    float pk = __shfl(p, kki);               // per-lane src index, all lanes active
    int nk = (ib + kki / 7) * 28 + (jb + kki % 7);
    acc += pk * v3[base + (size_t)nk * 32 + d];
  }
  acc += __shfl_xor(acc, 32);                // combine halves
  if (l < 32)
    ob[(((size_t)b * 784 + m) * 6 + h) * 32 + l] = acc / sum;
}

extern "C" void kernel_launch(void* const* d_in, const int* in_sizes, int n_in,
                              void* d_out, int out_size, void* d_ws, size_t ws_size,
                              hipStream_t stream) {
  (void)in_sizes; (void)n_in; (void)out_size; (void)ws_size;
  const float* x        = (const float*)d_in[0];
  const float* convw    = (const float*)d_in[1];
  const float* qw       = (const float*)d_in[2];
  const float* kw       = (const float*)d_in[3];
  const float* vw       = (const float*)d_in[4];
  const float* ln_in_g  = (const float*)d_in[5];
  const float* ln_in_b  = (const float*)d_in[6];
  const float* ln_out_g = (const float*)d_in[7];
  const float* ln_out_b = (const float*)d_in[8];
  const float* ln_at_g  = (const float*)d_in[9];
  const float* ln_at_b  = (const float*)d_in[10];
  const float* ln_ml_g  = (const float*)d_in[11];
  const float* ln_ml_b  = (const float*)d_in[12];
  const float* gw1      = (const float*)d_in[13];
  const float* gb1      = (const float*)d_in[14];
  const float* gw2      = (const float*)d_in[15];
  const float* gb2      = (const float*)d_in[16];
  const float* tau      = (const float*)d_in[17];
  const float* rpb      = (const float*)d_in[18];
  const float* bln1g    = (const float*)d_in[19];
  const float* bln1b    = (const float*)d_in[20];
  const float* bln2g    = (const float*)d_in[21];
  const float* bln2b    = (const float*)d_in[22];
  const float* bqkvw    = (const float*)d_in[23];
  const float* bprojw   = (const float*)d_in[24];
  const float* bprojb   = (const float*)d_in[25];
  const float* bmw1     = (const float*)d_in[26];
  const float* bmb1     = (const float*)d_in[27];
  const float* bmw2     = (const float*)d_in[28];
  const float* bmb2     = (const float*)d_in[29];

  float* XOUT = (float*)d_out;  // residual stream lives in d_out (f32, 8*784*192)

  float* W = (float*)d_ws;
  size_t off = 0;
  float* XN96  = W + off; off += (size_t)25088 * 96;   // LN(x); later aliased as KbT
  float* XN192 = W + off; off += (size_t)6272 * 192;
  float* Kb    = W + off; off += (size_t)25088 * 96;
  float* Vb    = W + off; off += (size_t)25088 * 192;
  float* Qb    = W + off; off += (size_t)6272 * 96;
  float* Mb    = W + off; off += (size_t)25088;
  float* Zb    = W + off; off += (size_t)25088;
  float* H1    = W + off; off += (size_t)6272 * 576;   // also QKVRAW
  float* T2    = W + off; off += (size_t)6272 * 192;   // also CRAW
  float* CT    = W + off; off += (size_t)784 * 16;
  float* ST    = W + off; off += (size_t)784 * 16;
  short* WBH   = (short*)(W + off); off += (size_t)548352 + 16;  // hi arena
  short* WBL   = (short*)(W + off); off += (size_t)548352 + 16;  // lo arena
  const size_t O_c = 0, O_k = 165888, O_v = 175104, O_q = 193536,
               O_g1 = 211968, O_g2 = 285696, O_qkv = 359424, O_p = 580608,
               O_m1 = 654336, O_m2 = 875520;
  // aliases
  float* CRAW = T2;
  float* QKVRAW = H1;
  float* KbT = XN96;                    // XN96 dead after k/v GEMMs
  float* Q3 = Kb;                       // block phase: Kb/Vb dead
  float* K3 = Kb + (size_t)1204224;
  float* V3 = Vb;
  float* OB = Vb + (size_t)1204224;

  k_castw<<<4284, 256, 0, stream>>>(convw, kw, vw, qw, gw1, gw2, bqkvw, bprojw,
                                    bmw1, bmw2, WBH, WBL);
  k_rope<<<49, 256, 0, stream>>>(CT, ST);

  // conv (implicit GEMM, K=864) + LN
  k_mgemm<0, 1><<<dim3(98, 3), 256, 0, stream>>>(x, WBH + O_c, WBL + O_c, nullptr,
                                                 CRAW, 6272, 192, 864);
  k_ln_epi<0><<<1568, 256, 0, stream>>>(CRAW, ln_out_g, ln_out_b, XOUT, 6272);

  // k,v projections
  k_ln<96><<<6272, 256, 0, stream>>>(x, ln_in_g, ln_in_b, XN96, 25088);
  k_mgemm<0, 0><<<dim3(392, 2), 256, 0, stream>>>(XN96, WBH + O_k, WBL + O_k, nullptr,
                                                  Kb, 25088, 96, 96);
  k_mgemm<0, 0><<<dim3(392, 3), 256, 0, stream>>>(XN96, WBH + O_v, WBL + O_v, nullptr,
                                                  Vb, 25088, 192, 96);
  k_tr<<<(25088 * 96 + 255) / 256, 256, 0, stream>>>(Kb, KbT, 25088, 96);

  for (int it = 0; it < 3; ++it) {
    k_ln<192><<<1568, 256, 0, stream>>>(XOUT, ln_out_g, ln_out_b, XN192, 6272);
    k_mgemm<0, 0><<<dim3(98, 2), 256, 0, stream>>>(XN192, WBH + O_q, WBL + O_q, nullptr,
                                                   Qb, 6272, 96, 192);
    k_pass1<<<98, 256, 0, stream>>>(KbT, Qb, rpb, tau, Mb, Zb);
    k_pass2<<<6272, 192, 0, stream>>>(Kb, Qb, Vb, Mb, Zb, rpb, tau, ln_at_g, ln_at_b, XOUT);
    k_mgemm<1, 0><<<dim3(98, 6), 256, 0, stream>>>(XOUT, WBH + O_g1, WBL + O_g1, gb1,
                                                   H1, 6272, 384, 192);
    k_mgemm<0, 0><<<dim3(98, 3), 256, 0, stream>>>(H1, WBH + O_g2, WBL + O_g2, gb2,
                                                   T2, 6272, 192, 384);
    k_ln_epi<1><<<1568, 256, 0, stream>>>(T2, ln_ml_g, ln_ml_b, XOUT, 6272);
  }

  for (int i = 0; i < 2; ++i) {
    k_ln<192><<<1568, 256, 0, stream>>>(XOUT, bln1g + (size_t)i * 192,
                                        bln1b + (size_t)i * 192, XN192, 6272);
    k_mgemm<0, 0><<<dim3(98, 9), 256, 0, stream>>>(XN192, WBH + O_qkv + (size_t)i * 110592,
        WBL + O_qkv + (size_t)i * 110592, nullptr, QKVRAW, 6272, 576, 192);
    k_rope_scatter<<<(8 * 784 * 576 + 255) / 256, 256, 0, stream>>>(QKVRAW, CT, ST, Q3, K3, V3);
    k_attn<<<9408, 256, 0, stream>>>(Q3, K3, V3, OB);
    k_mgemm<2, 0><<<dim3(98, 3), 256, 0, stream>>>(OB, WBH + O_p + (size_t)i * 36864,
        WBL + O_p + (size_t)i * 36864, bprojb + (size_t)i * 192, XOUT, 6272, 192, 192);
    k_ln<192><<<1568, 256, 0, stream>>>(XOUT, bln2g + (size_t)i * 192,
                                        bln2b + (size_t)i * 192, XN192, 6272);
    k_mgemm<1, 0><<<dim3(98, 9), 256, 0, stream>>>(XN192, WBH + O_m1 + (size_t)i * 110592,
        WBL + O_m1 + (size_t)i * 110592, bmb1 + (size_t)i * 576, H1, 6272, 576, 192);
    k_mgemm<2, 0><<<dim3(98, 3), 256, 0, stream>>>(H1, WBH + O_m2 + (size_t)i * 110592,
        WBL + O_m2 + (size_t)i * 110592, bmb2 + (size_t)i * 192, XOUT, 6272, 192, 576);
  }
}

// Round 11
// 773.231 us; speedup vs baseline: 1.1574x; 1.0487x over previous
//
#include <hip/hip_runtime.h>
#include <hip/hip_bf16.h>

#define DEV __device__ __forceinline__

typedef __attribute__((ext_vector_type(8))) short short8;
typedef __attribute__((ext_vector_type(4))) float f32x4;

DEV unsigned short f2b(float f) {
  union { float f; unsigned u; } v; v.f = f;
  unsigned r = v.u + 0x7FFFu + ((v.u >> 16) & 1u);  // RNE
  return (unsigned short)(r >> 16);
}
DEV float b2f16(unsigned short b) {
  union { unsigned u; float f; } v; v.u = ((unsigned)b) << 16;
  return v.f;
}

// ---------------- fused weight cast f32 -> bf16 hi/lo arenas ----------------
// conv weights are stored TAP-MAJOR: dst[co*864 + k9*96 + ci] = src[co*864 + ci*9 + k9]
__global__ void k_castw(const float* __restrict__ s0, const float* __restrict__ s1,
    const float* __restrict__ s2, const float* __restrict__ s3,
    const float* __restrict__ s4, const float* __restrict__ s5,
    const float* __restrict__ s6, const float* __restrict__ s7,
    const float* __restrict__ s8, const float* __restrict__ s9,
    short* __restrict__ dh, short* __restrict__ dl) {
  int idx = blockIdx.x * 256 + threadIdx.x;
  if (idx >= 1096704) return;
  float v;
  if (idx < 165888) {
    int co = idx / 864, rem = idx % 864;
    int k9 = rem / 96, ci = rem % 96;
    v = s0[co * 864 + ci * 9 + k9];
  } else {
    const float* src; int base;
    if      (idx < 175104) { src = s1; base = 165888; }
    else if (idx < 193536) { src = s2; base = 175104; }
    else if (idx < 211968) { src = s3; base = 193536; }
    else if (idx < 285696) { src = s4; base = 211968; }
    else if (idx < 359424) { src = s5; base = 285696; }
    else if (idx < 580608) { src = s6; base = 359424; }
    else if (idx < 654336) { src = s7; base = 580608; }
    else if (idx < 875520) { src = s8; base = 654336; }
    else                   { src = s9; base = 875520; }
    v = src[idx - base];
  }
  unsigned short h = f2b(v);
  dh[idx] = (short)h;
  dl[idx] = (short)f2b(v - b2f16(h));
}

// ---------------- generic transpose: src[R][C] -> dst[C][R] ----------------
__global__ void k_tr(const float* __restrict__ src, float* __restrict__ dst,
                     int R, int C) {
  int idx = blockIdx.x * 256 + threadIdx.x;
  if (idx >= R * C) return;
  int r = idx / C, c = idx % C;
  dst[(size_t)c * R + r] = src[idx];
}

// ---------------- rope tables: ct/st [784][16] ----------------
__global__ void k_rope(float* ct, float* st) {
  int idx = blockIdx.x * 256 + threadIdx.x;
  if (idx >= 784 * 16) return;
  int n = idx >> 4, j = idx & 15;
  float inv = powf(10000.f, -(float)(2 * j) / 32.f);
  float ang = (float)n * inv;
  ct[idx] = cosf(ang);
  st[idx] = sinf(ang);
}

// ---------------- LN over last dim D, wave per token, 4 tokens/block ----------------
template<int D>
__global__ __launch_bounds__(256) void k_ln(const float* __restrict__ in,
    const float* __restrict__ g, const float* __restrict__ b,
    float* __restrict__ out, int M) {
  int tok = blockIdx.x * 4 + (threadIdx.x >> 6);
  int l = threadIdx.x & 63;
  if (tok >= M) return;  // wave-uniform
  const float* row = in + (size_t)tok * D;
  constexpr int E = (D + 63) / 64;
  float v[E];
  float s = 0.f, s2 = 0.f;
#pragma unroll
  for (int e = 0; e < E; ++e) {
    int i = e * 64 + l;
    float x = (i < D) ? row[i] : 0.f;
    v[e] = x; s += x; s2 += x * x;
  }
  for (int off = 32; off; off >>= 1) { s += __shfl_xor(s, off); s2 += __shfl_xor(s2, off); }
  float mean = s / D, var = s2 / D - mean * mean;
  float rstd = rsqrtf(var + 1e-5f);
  float* orow = out + (size_t)tok * D;
#pragma unroll
  for (int e = 0; e < E; ++e) {
    int i = e * 64 + l;
    if (i < D) orow[i] = (v[e] - mean) * rstd * g[i] + b[i];
  }
}

// ---------------- LN epilogue over D=192: out = (write|add) LN(raw) ----------------
template<int ADD>
__global__ __launch_bounds__(256) void k_ln_epi(const float* __restrict__ raw,
    const float* __restrict__ g, const float* __restrict__ b,
    float* __restrict__ out, int M) {
  int tok = blockIdx.x * 4 + (threadIdx.x >> 6);
  int l = threadIdx.x & 63;
  if (tok >= M) return;
  const float* row = raw + (size_t)tok * 192;
  float v[3];
  float s = 0.f, s2 = 0.f;
#pragma unroll
  for (int e = 0; e < 3; ++e) {
    float x = row[e * 64 + l];
    v[e] = x; s += x; s2 += x * x;
  }
  for (int off = 32; off; off >>= 1) { s += __shfl_xor(s, off); s2 += __shfl_xor(s2, off); }
  float mean = s / 192.f, var = s2 / 192.f - mean * mean;
  float rstd = rsqrtf(var + 1e-5f);
  float* orow = out + (size_t)tok * 192;
#pragma unroll
  for (int e = 0; e < 3; ++e) {
    int i = e * 64 + l;
    float r = (v[e] - mean) * rstd * g[i] + b[i];
    if (ADD) orow[i] += r; else orow[i] = r;
  }
}

// ---------------- MFMA bf16x2 split GEMM: C = A @ W^T, f32-grade accuracy ----------------
// 64x64 tile, BK=32, 256 threads = 4 waves (2x2), per-wave 2x2 16x16 frags.
// acc = ah*bh + ah*bl + al*bh (al*bl dropped, ~eps^2).
// A-staging: octet assembled in short8 regs, one 16B LDS store (no 2B scalar writes).
// EPI: 0 = store, 1 = gelu+store, 2 = add-into-C.
// CONV: im2col from x[b][56][56][96], weights TAP-MAJOR (k = k9*96+ci) -> float4 loads.
template<int EPI, int CONV>
__global__ __launch_bounds__(256) void k_mgemm(
    const float* __restrict__ A, const short* __restrict__ WH,
    const short* __restrict__ WL, const float* __restrict__ bias,
    float* __restrict__ C, int M, int N, int K) {
  __shared__ short AsH[64][40], AsL[64][40];
  __shared__ short BsH[64][40], BsL[64][40];
  int t = threadIdx.x;
  int m0 = blockIdx.x * 64, n0 = blockIdx.y * 64;
  int sr = t >> 2, sq = (t & 3) * 8;       // stage: row, k-offset (8 elems/thread)
  int lane = t & 63, w = t >> 6, wm = w >> 1, wn = w & 1;
  int fr = lane & 15, fq = lane >> 4;      // frag row, k-block
  f32x4 acc[2][2];
#pragma unroll
  for (int i = 0; i < 2; ++i)
#pragma unroll
    for (int j = 0; j < 2; ++j) acc[i][j] = (f32x4){0.f, 0.f, 0.f, 0.f};

  for (int kt = 0; kt < K; kt += 32) {
    // ---- A tile: 64 rows x 32 k -> hi/lo bf16, 16B vector writes ----
    short8 vh, vl;
    if (CONV) {
      int m = m0 + sr;
      int b = m / 784, rm = m % 784, ho = rm / 28, wo = rm % 28;
      int k = kt + sq;                      // octet never straddles a tap (96 % 8 == 0)
      int k9 = k / 96, ci0 = k % 96;
      int hi = 2 * ho - 1 + k9 / 3, wi = 2 * wo - 1 + k9 % 3;
      if (hi >= 0 && hi < 56 && wi >= 0 && wi < 56) {
        const float* src = &A[((size_t)b * 3136 + hi * 56 + wi) * 96 + ci0];
        float4 a0 = *(const float4*)src;
        float4 a1 = *(const float4*)(src + 4);
        float av[8] = {a0.x, a0.y, a0.z, a0.w, a1.x, a1.y, a1.z, a1.w};
#pragma unroll
        for (int j = 0; j < 8; ++j) {
          unsigned short h = f2b(av[j]);
          vh[j] = (short)h;
          vl[j] = (short)f2b(av[j] - b2f16(h));
        }
      } else {
#pragma unroll
        for (int j = 0; j < 8; ++j) { vh[j] = 0; vl[j] = 0; }
      }
    } else {
      const float4 a0 = *(const float4*)&A[(size_t)(m0 + sr) * K + kt + sq];
      const float4 a1 = *(const float4*)&A[(size_t)(m0 + sr) * K + kt + sq + 4];
      float av[8] = {a0.x, a0.y, a0.z, a0.w, a1.x, a1.y, a1.z, a1.w};
#pragma unroll
      for (int j = 0; j < 8; ++j) {
        unsigned short h = f2b(av[j]);
        vh[j] = (short)h;
        vl[j] = (short)f2b(av[j] - b2f16(h));
      }
    }
    *(short8*)&AsH[sr][sq] = vh;
    *(short8*)&AsL[sr][sq] = vl;
    // ---- B tile: Bs[n][k] = W[n0+n][kt+k] (pre-split bf16, 16B vector copies) ----
    {
      int n = n0 + sr;
      if (n < N) {
        *(short8*)&BsH[sr][sq] = *(const short8*)&WH[(size_t)n * K + kt + sq];
        *(short8*)&BsL[sr][sq] = *(const short8*)&WL[(size_t)n * K + kt + sq];
      } else {
        short8 z = {0, 0, 0, 0, 0, 0, 0, 0};
        *(short8*)&BsH[sr][sq] = z;
        *(short8*)&BsL[sr][sq] = z;
      }
    }
    __syncthreads();
    short8 ah[2], al[2], bh[2], bl[2];
#pragma unroll
    for (int s = 0; s < 2; ++s) {
      ah[s] = *(const short8*)&AsH[wm * 32 + s * 16 + fr][fq * 8];
      al[s] = *(const short8*)&AsL[wm * 32 + s * 16 + fr][fq * 8];
      bh[s] = *(const short8*)&BsH[wn * 32 + s * 16 + fr][fq * 8];
      bl[s] = *(const short8*)&BsL[wn * 32 + s * 16 + fr][fq * 8];
    }
#pragma unroll
    for (int i = 0; i < 2; ++i)
#pragma unroll
      for (int j = 0; j < 2; ++j) {
        acc[i][j] = __builtin_amdgcn_mfma_f32_16x16x32_bf16(ah[i], bh[j], acc[i][j], 0, 0, 0);
        acc[i][j] = __builtin_amdgcn_mfma_f32_16x16x32_bf16(ah[i], bl[j], acc[i][j], 0, 0, 0);
        acc[i][j] = __builtin_amdgcn_mfma_f32_16x16x32_bf16(al[i], bh[j], acc[i][j], 0, 0, 0);
      }
    __syncthreads();
  }
  // epilogue: C/D layout col = lane&15, row = (lane>>4)*4 + r   [m89]
#pragma unroll
  for (int i = 0; i < 2; ++i) {
#pragma unroll
    for (int j = 0; j < 2; ++j) {
      int n = n0 + wn * 32 + j * 16 + fr;
      if (n >= N) continue;
#pragma unroll
      for (int r = 0; r < 4; ++r) {
        int m = m0 + wm * 32 + i * 16 + fq * 4 + r;
        float v = acc[i][j][r];
        if (bias) v += bias[n];
        if (EPI == 1) v = 0.5f * v * (1.f + erff(v * 0.70710678118654752f));
        if (EPI == 2) C[(size_t)m * N + n] += v;
        else          C[(size_t)m * N + n] = v;
      }
    }
  }
}

// ---------------- pass1: per-input softmax stats; kkT[96][25088] coalesced ----------------
__global__ void k_pass1(const float* __restrict__ kkT, const float* __restrict__ q,
    const float* __restrict__ rpb, const float* __restrict__ tau,
    float* __restrict__ M, float* __restrict__ Z) {
  int id = blockIdx.x * 256 + threadIdx.x;
  if (id >= 8 * 3136) return;
  int b = id / 3136, n = id % 3136;
  int r = n / 56, c = n % 56, r0 = r >> 1, c0 = c >> 1;
  int oi[9];
#pragma unroll
  for (int kki = 0; kki < 9; ++kki) {
    int dr = kki / 3 - 1, dc = kki % 3 - 1;
    int rr = min(max(r0 + dr, 0), 27), cc = min(max(c0 + dc, 0), 27);
    oi[kki] = rr * 28 + cc;
  }
  float scale = expf(tau[0]);
  float lg[9]; bool keep[9];
  float mx = -1e30f;
#pragma unroll
  for (int kki = 0; kki < 9; ++kki) {
    bool kp = true;
#pragma unroll
    for (int k2 = kki + 1; k2 < 9; ++k2) if (oi[k2] == oi[kki]) kp = false;
    keep[kki] = kp;
    if (kp) {
      const float* qr = q + ((size_t)b * 784 + oi[kki]) * 96;
      float d = 0.f;
      for (int i = 0; i < 96; ++i) d += kkT[(size_t)i * 25088 + id] * qr[i];
      lg[kki] = d * scale + rpb[kki];
      mx = fmaxf(mx, lg[kki]);
    } else lg[kki] = -1e30f;
  }
  float z = 0.f;
#pragma unroll
  for (int kki = 0; kki < 9; ++kki) if (keep[kki]) z += expf(lg[kki] - mx);
  M[id] = mx; Z[id] = z;
}

// ---------------- pass2: gather contributors, upd, /denom, LN, residual ----------------
__global__ __launch_bounds__(192) void k_pass2(const float* __restrict__ kk,
    const float* __restrict__ q, const float* __restrict__ vv,
    const float* __restrict__ M, const float* __restrict__ Z,
    const float* __restrict__ rpb, const float* __restrict__ tau,
    const float* __restrict__ g, const float* __restrict__ bb, float* __restrict__ xout) {
  int blk = blockIdx.x, b = blk / 784, m = blk % 784;
  int r2 = m / 28, c2 = m % 28;
  int r0lo = (r2 == 0) ? 0 : r2 - 1, r0hi = (r2 == 27) ? 27 : r2 + 1;
  int c0lo = (c2 == 0) ? 0 : c2 - 1, c0hi = (c2 == 27) ? 27 : c2 + 1;
  int nrow = 2 * (r0hi - r0lo + 1), ncol = 2 * (c0hi - c0lo + 1);
  int cnt = nrow * ncol;  // <= 36
  __shared__ float qm[96], p[36];
  __shared__ int nlist[36];
  __shared__ float2 red[192];
  int t = threadIdx.x;
  if (t < 96) qm[t] = q[(size_t)blk * 96 + t];
  __syncthreads();
  if (t < cnt) {
    int rr = 2 * r0lo + t / ncol, cc = 2 * c0lo + t % ncol;
    int n = rr * 56 + cc, rr0 = rr >> 1, cc0 = cc >> 1;
    int kkf = 0;
#pragma unroll
    for (int kki = 0; kki < 9; ++kki) {
      int dr = kki / 3 - 1, dc = kki % 3 - 1;
      int ra = min(max(rr0 + dr, 0), 27), ca = min(max(cc0 + dc, 0), 27);
      if (ra == r2 && ca == c2) kkf = kki;  // last-kk-wins (matches numpy overwrite)
    }
    const float* krow = kk + ((size_t)b * 3136 + n) * 96;
    float d = 0.f;
    for (int i = 0; i < 96; ++i) d += krow[i] * qm[i];
    float scale = expf(tau[0]);
    float lg = d * scale + rpb[kkf];
    size_t idn = (size_t)b * 3136 + n;
    p[t] = expf(lg - M[idn]) / Z[idn];
    nlist[t] = n;
  }
  __syncthreads();
  float denom = 0.f;
  for (int jn = 0; jn < cnt; ++jn) denom += p[jn];
  float acc = 0.f;
  for (int jn = 0; jn < cnt; ++jn)
    acc += p[jn] * vv[((size_t)b * 3136 + nlist[jn]) * 192 + t];
  float upd = acc / (denom + 1e-8f);
  red[t] = make_float2(upd, upd * upd);
  __syncthreads();
  for (int s = 128; s > 0; s >>= 1) {
    if (t < s && t + s < 192) { red[t].x += red[t + s].x; red[t].y += red[t + s].y; }
    __syncthreads();
  }
  float mean = red[0].x / 192.f, var = red[0].y / 192.f - mean * mean;
  float rstd = rsqrtf(var + 1e-5f);
  xout[(size_t)blk * 192 + t] += (upd - mean) * rstd * g[t] + bb[t];
}

// ---------------- rope + scatter: RAW[6272][576] -> q3/k3/v3 [b][6][784][32] ----------------
__global__ void k_rope_scatter(const float* __restrict__ raw,
    const float* __restrict__ ct, const float* __restrict__ st,
    float* __restrict__ q3, float* __restrict__ k3, float* __restrict__ v3) {
  int idx = blockIdx.x * 256 + threadIdx.x;
  if (idx >= 8 * 784 * 576) return;
  int tok = idx / 576, d5 = idx % 576;
  int b = tok / 784, m = tok % 784;
  int sec = d5 / 192, d = d5 % 192, h = d / 32, dh = d % 32;
  float me = raw[idx], val;
  if (sec < 2) {
    float pa = raw[(size_t)tok * 576 + sec * 192 + (d ^ 1)];
    int j = dh >> 1;
    float cc = ct[m * 16 + j], ss = st[m * 16 + j];
    val = (dh & 1) ? (me * cc + pa * ss) : (me * cc - pa * ss);
  } else val = me;
  float* dst = (sec == 0) ? q3 : ((sec == 1) ? k3 : v3);
  dst[(((size_t)b * 6 + h) * 784 + m) * 32 + dh] = val;
}

// ---------------- neighborhood attention 7x7: wide, vectorized, split-PV ----------------
__global__ __launch_bounds__(256) void k_attn(const float* __restrict__ q3,
    const float* __restrict__ k3, const float* __restrict__ v3, float* __restrict__ ob) {
  int bid = blockIdx.x;
  int swz = (bid & 7) * 1176 + (bid >> 3);  // bijective on [0,9408)
  int unit = swz * 4 + (threadIdx.x >> 6);
  int l = threadIdx.x & 63;
  int b = unit / (6 * 784), rem = unit % (6 * 784), h = rem / 784, m = rem % 784;
  int i = m / 28, j = m % 28;
  int ib = min(max(i, 3), 24) - 3, jb = min(max(j, 3), 24) - 3;
  size_t base = (size_t)(b * 6 + h) * 784 * 32;
  const float4* q4 = (const float4*)(q3 + base + (size_t)m * 32);
  float4 qv[8];
#pragma unroll
  for (int e = 0; e < 8; ++e) qv[e] = q4[e];
  float logit = -1e30f;
  if (l < 49) {
    int nk = (ib + l / 7) * 28 + (jb + l % 7);
    const float4* k4 = (const float4*)(k3 + base + (size_t)nk * 32);
    float a = 0.f;
#pragma unroll
    for (int e = 0; e < 8; ++e) {
      float4 kv = k4[e];
      a += qv[e].x * kv.x + qv[e].y * kv.y + qv[e].z * kv.z + qv[e].w * kv.w;
    }
    logit = a * 0.17677669529663687f;  // 32^-0.5
  }
  float mx = logit;
  for (int off = 32; off; off >>= 1) mx = fmaxf(mx, __shfl_xor(mx, off));
  float p = (l < 49) ? expf(logit - mx) : 0.f;
  float sum = p;
  for (int off = 32; off; off >>= 1) sum += __shfl_xor(sum, off);
  int half = l >> 5, d = l & 31;
  int kbeg = half ? 25 : 0, kend = half ? 49 : 25;
  float acc = 0.f;
  for (int kki = kbeg; kki < kend; ++kki) {
    float pk = __shfl(p, kki);
    int nk = (ib + kki / 7) * 28 + (jb + kki % 7);
    acc += pk * v3[base + (size_t)nk * 32 + d];
  }
  acc += __shfl_xor(acc, 32);
  if (l < 32)
    ob[(((size_t)b * 784 + m) * 6 + h) * 32 + l] = acc / sum;
}

extern "C" void kernel_launch(void* const* d_in, const int* in_sizes, int n_in,
                              void* d_out, int out_size, void* d_ws, size_t ws_size,
                              hipStream_t stream) {
  (void)in_sizes; (void)n_in; (void)out_size; (void)ws_size;
  const float* x        = (const float*)d_in[0];
  const float* convw    = (const float*)d_in[1];
  const float* qw       = (const float*)d_in[2];
  const float* kw       = (const float*)d_in[3];
  const float* vw       = (const float*)d_in[4];
  const float* ln_in_g  = (const float*)d_in[5];
  const float* ln_in_b  = (const float*)d_in[6];
  const float* ln_out_g = (const float*)d_in[7];
  const float* ln_out_b = (const float*)d_in[8];
  const float* ln_at_g  = (const float*)d_in[9];
  const float* ln_at_b  = (const float*)d_in[10];
  const float* ln_ml_g  = (const float*)d_in[11];
  const float* ln_ml_b  = (const float*)d_in[12];
  const float* gw1      = (const float*)d_in[13];
  const float* gb1      = (const float*)d_in[14];
  const float* gw2      = (const float*)d_in[15];
  const float* gb2      = (const float*)d_in[16];
  const float* tau      = (const float*)d_in[17];
  const float* rpb      = (const float*)d_in[18];
  const float* bln1g    = (const float*)d_in[19];
  const float* bln1b    = (const float*)d_in[20];
  const float* bln2g    = (const float*)d_in[21];
  const float* bln2b    = (const float*)d_in[22];
  const float* bqkvw    = (const float*)d_in[23];
  const float* bprojw   = (const float*)d_in[24];
  const float* bprojb   = (const float*)d_in[25];
  const float* bmw1     = (const float*)d_in[26];
  const float* bmb1     = (const float*)d_in[27];
  const float* bmw2     = (const float*)d_in[28];
  const float* bmb2     = (const float*)d_in[29];

  float* XOUT = (float*)d_out;  // residual stream lives in d_out (f32, 8*784*192)

  float* W = (float*)d_ws;
  size_t off = 0;
  float* XN96  = W + off; off += (size_t)25088 * 96;   // LN(x); later aliased as KbT
  float* XN192 = W + off; off += (size_t)6272 * 192;
  float* Kb    = W + off; off += (size_t)25088 * 96;
  float* Vb    = W + off; off += (size_t)25088 * 192;
  float* Qb    = W + off; off += (size_t)6272 * 96;
  float* Mb    = W + off; off += (size_t)25088;
  float* Zb    = W + off; off += (size_t)25088;
  float* H1    = W + off; off += (size_t)6272 * 576;   // also QKVRAW
  float* T2    = W + off; off += (size_t)6272 * 192;   // also CRAW
  float* CT    = W + off; off += (size_t)784 * 16;
  float* ST    = W + off; off += (size_t)784 * 16;
  short* WBH   = (short*)(W + off); off += (size_t)548352 + 16;  // hi arena
  short* WBL   = (short*)(W + off); off += (size_t)548352 + 16;  // lo arena
  const size_t O_c = 0, O_k = 165888, O_v = 175104, O_q = 193536,
               O_g1 = 211968, O_g2 = 285696, O_qkv = 359424, O_p = 580608,
               O_m1 = 654336, O_m2 = 875520;
  // aliases
  float* CRAW = T2;
  float* QKVRAW = H1;
  float* KbT = XN96;                    // XN96 dead after k/v GEMMs
  float* Q3 = Kb;                       // block phase: Kb/Vb dead
  float* K3 = Kb + (size_t)1204224;
  float* V3 = Vb;
  float* OB = Vb + (size_t)1204224;

  k_castw<<<4284, 256, 0, stream>>>(convw, kw, vw, qw, gw1, gw2, bqkvw, bprojw,
                                    bmw1, bmw2, WBH, WBL);
  k_rope<<<49, 256, 0, stream>>>(CT, ST);

  // conv (implicit GEMM, K=864, tap-major weights) + LN
  k_mgemm<0, 1><<<dim3(98, 3), 256, 0, stream>>>(x, WBH + O_c, WBL + O_c, nullptr,
                                                 CRAW, 6272, 192, 864);
  k_ln_epi<0><<<1568, 256, 0, stream>>>(CRAW, ln_out_g, ln_out_b, XOUT, 6272);

  // k,v projections
  k_ln<96><<<6272, 256, 0, stream>>>(x, ln_in_g, ln_in_b, XN96, 25088);
  k_mgemm<0, 0><<<dim3(392, 2), 256, 0, stream>>>(XN96, WBH + O_k, WBL + O_k, nullptr,
                                                  Kb, 25088, 96, 96);
  k_mgemm<0, 0><<<dim3(392, 3), 256, 0, stream>>>(XN96, WBH + O_v, WBL + O_v, nullptr,
                                                  Vb, 25088, 192, 96);
  k_tr<<<(25088 * 96 + 255) / 256, 256, 0, stream>>>(Kb, KbT, 25088, 96);

  for (int it = 0; it < 3; ++it) {
    k_ln<192><<<1568, 256, 0, stream>>>(XOUT, ln_out_g, ln_out_b, XN192, 6272);
    k_mgemm<0, 0><<<dim3(98, 2), 256, 0, stream>>>(XN192, WBH + O_q, WBL + O_q, nullptr,
                                                   Qb, 6272, 96, 192);
    k_pass1<<<98, 256, 0, stream>>>(KbT, Qb, rpb, tau, Mb, Zb);
    k_pass2<<<6272, 192, 0, stream>>>(Kb, Qb, Vb, Mb, Zb, rpb, tau, ln_at_g, ln_at_b, XOUT);
    k_mgemm<1, 0><<<dim3(98, 6), 256, 0, stream>>>(XOUT, WBH + O_g1, WBL + O_g1, gb1,
                                                   H1, 6272, 384, 192);
    k_mgemm<0, 0><<<dim3(98, 3), 256, 0, stream>>>(H1, WBH + O_g2, WBL + O_g2, gb2,
                                                   T2, 6272, 192, 384);
    k_ln_epi<1><<<1568, 256, 0, stream>>>(T2, ln_ml_g, ln_ml_b, XOUT, 6272);
  }

  for (int i = 0; i < 2; ++i) {
    k_ln<192><<<1568, 256, 0, stream>>>(XOUT, bln1g + (size_t)i * 192,
                                        bln1b + (size_t)i * 192, XN192, 6272);
    k_mgemm<0, 0><<<dim3(98, 9), 256, 0, stream>>>(XN192, WBH + O_qkv + (size_t)i * 110592,
        WBL + O_qkv + (size_t)i * 110592, nullptr, QKVRAW, 6272, 576, 192);
    k_rope_scatter<<<(8 * 784 * 576 + 255) / 256, 256, 0, stream>>>(QKVRAW, CT, ST, Q3, K3, V3);
    k_attn<<<9408, 256, 0, stream>>>(Q3, K3, V3, OB);
    k_mgemm<2, 0><<<dim3(98, 3), 256, 0, stream>>>(OB, WBH + O_p + (size_t)i * 36864,
        WBL + O_p + (size_t)i * 36864, bprojb + (size_t)i * 192, XOUT, 6272, 192, 192);
    k_ln<192><<<1568, 256, 0, stream>>>(XOUT, bln2g + (size_t)i * 192,
                                        bln2b + (size_t)i * 192, XN192, 6272);
    k_mgemm<1, 0><<<dim3(98, 9), 256, 0, stream>>>(XN192, WBH + O_m1 + (size_t)i * 110592,
        WBL + O_m1 + (size_t)i * 110592, bmb1 + (size_t)i * 576, H1, 6272, 576, 192);
    k_mgemm<2, 0><<<dim3(98, 3), 256, 0, stream>>>(H1, WBH + O_m2 + (size_t)i * 110592,
        WBL + O_m2 + (size_t)i * 110592, bmb2 + (size_t)i * 192, XOUT, 6272, 192, 576);
  }
}

// Round 12
// 745.821 us; speedup vs baseline: 1.1999x; 1.0368x over previous
//
#include <hip/hip_runtime.h>
#include <hip/hip_bf16.h>

#define DEV __device__ __forceinline__

typedef __attribute__((ext_vector_type(8))) short short8;
typedef __attribute__((ext_vector_type(4))) float f32x4;

DEV unsigned short f2b(float f) {
  union { float f; unsigned u; } v; v.f = f;
  unsigned r = v.u + 0x7FFFu + ((v.u >> 16) & 1u);  // RNE
  return (unsigned short)(r >> 16);
}
DEV float b2f16(unsigned short b) {
  union { unsigned u; float f; } v; v.u = ((unsigned)b) << 16;
  return v.f;
}

// ---------------- fused weight cast f32 -> bf16 hi/lo arenas ----------------
// conv weights are stored TAP-MAJOR: dst[co*864 + k9*96 + ci] = src[co*864 + ci*9 + k9]
__global__ void k_castw(const float* __restrict__ s0, const float* __restrict__ s1,
    const float* __restrict__ s2, const float* __restrict__ s3,
    const float* __restrict__ s4, const float* __restrict__ s5,
    const float* __restrict__ s6, const float* __restrict__ s7,
    const float* __restrict__ s8, const float* __restrict__ s9,
    short* __restrict__ dh, short* __restrict__ dl) {
  int idx = blockIdx.x * 256 + threadIdx.x;
  if (idx >= 1096704) return;
  float v;
  if (idx < 165888) {
    int co = idx / 864, rem = idx % 864;
    int k9 = rem / 96, ci = rem % 96;
    v = s0[co * 864 + ci * 9 + k9];
  } else {
    const float* src; int base;
    if      (idx < 175104) { src = s1; base = 165888; }
    else if (idx < 193536) { src = s2; base = 175104; }
    else if (idx < 211968) { src = s3; base = 193536; }
    else if (idx < 285696) { src = s4; base = 211968; }
    else if (idx < 359424) { src = s5; base = 285696; }
    else if (idx < 580608) { src = s6; base = 359424; }
    else if (idx < 654336) { src = s7; base = 580608; }
    else if (idx < 875520) { src = s8; base = 654336; }
    else                   { src = s9; base = 875520; }
    v = src[idx - base];
  }
  unsigned short h = f2b(v);
  dh[idx] = (short)h;
  dl[idx] = (short)f2b(v - b2f16(h));
}

// ---------------- rope tables: ct/st [784][16] ----------------
__global__ void k_rope(float* ct, float* st) {
  int idx = blockIdx.x * 256 + threadIdx.x;
  if (idx >= 784 * 16) return;
  int n = idx >> 4, j = idx & 15;
  float inv = powf(10000.f, -(float)(2 * j) / 32.f);
  float ang = (float)n * inv;
  ct[idx] = cosf(ang);
  st[idx] = sinf(ang);
}

// ---------------- LN over last dim D, wave per token, 4 tokens/block ----------------
template<int D>
__global__ __launch_bounds__(256) void k_ln(const float* __restrict__ in,
    const float* __restrict__ g, const float* __restrict__ b,
    float* __restrict__ out, int M) {
  int tok = blockIdx.x * 4 + (threadIdx.x >> 6);
  int l = threadIdx.x & 63;
  if (tok >= M) return;  // wave-uniform
  const float* row = in + (size_t)tok * D;
  constexpr int E = (D + 63) / 64;
  float v[E];
  float s = 0.f, s2 = 0.f;
#pragma unroll
  for (int e = 0; e < E; ++e) {
    int i = e * 64 + l;
    float x = (i < D) ? row[i] : 0.f;
    v[e] = x; s += x; s2 += x * x;
  }
  for (int off = 32; off; off >>= 1) { s += __shfl_xor(s, off); s2 += __shfl_xor(s2, off); }
  float mean = s / D, var = s2 / D - mean * mean;
  float rstd = rsqrtf(var + 1e-5f);
  float* orow = out + (size_t)tok * D;
#pragma unroll
  for (int e = 0; e < E; ++e) {
    int i = e * 64 + l;
    if (i < D) orow[i] = (v[e] - mean) * rstd * g[i] + b[i];
  }
}

// ---------------- LN epilogue over D=192: out = (write|add) LN(raw) ----------------
template<int ADD>
__global__ __launch_bounds__(256) void k_ln_epi(const float* __restrict__ raw,
    const float* __restrict__ g, const float* __restrict__ b,
    float* __restrict__ out, int M) {
  int tok = blockIdx.x * 4 + (threadIdx.x >> 6);
  int l = threadIdx.x & 63;
  if (tok >= M) return;
  const float* row = raw + (size_t)tok * 192;
  float v[3];
  float s = 0.f, s2 = 0.f;
#pragma unroll
  for (int e = 0; e < 3; ++e) {
    float x = row[e * 64 + l];
    v[e] = x; s += x; s2 += x * x;
  }
  for (int off = 32; off; off >>= 1) { s += __shfl_xor(s, off); s2 += __shfl_xor(s2, off); }
  float mean = s / 192.f, var = s2 / 192.f - mean * mean;
  float rstd = rsqrtf(var + 1e-5f);
  float* orow = out + (size_t)tok * 192;
#pragma unroll
  for (int e = 0; e < 3; ++e) {
    int i = e * 64 + l;
    float r = (v[e] - mean) * rstd * g[i] + b[i];
    if (ADD) orow[i] += r; else orow[i] = r;
  }
}

// ---------------- MFMA bf16x2 split GEMM: C = A @ W^T, f32-grade accuracy ----------------
// 64x64 tile, BK=32, 256 threads = 4 waves (2x2), per-wave 2x2 16x16 frags.
// acc = ah*bh + ah*bl + al*bh (al*bl dropped, ~eps^2).
// EPI: 0 store | 1 gelu+store | 2 add-into-C | 3 rope-scatter to o1/o2/o3 (qkv)
//      | 4 store C AND transposed float4 store to o1 (KbT).
// CONV: im2col from x[b][56][56][96], weights TAP-MAJOR (k = k9*96+ci).
template<int EPI, int CONV>
__global__ __launch_bounds__(256) void k_mgemm(
    const float* __restrict__ A, const short* __restrict__ WH,
    const short* __restrict__ WL, const float* __restrict__ bias,
    float* __restrict__ C, int M, int N, int K,
    const float* __restrict__ ct, const float* __restrict__ st,
    float* __restrict__ o1, float* __restrict__ o2, float* __restrict__ o3) {
  __shared__ short AsH[64][40], AsL[64][40];
  __shared__ short BsH[64][40], BsL[64][40];
  int t = threadIdx.x;
  int m0 = blockIdx.x * 64, n0 = blockIdx.y * 64;
  int sr = t >> 2, sq = (t & 3) * 8;       // stage: row, k-offset (8 elems/thread)
  int lane = t & 63, w = t >> 6, wm = w >> 1, wn = w & 1;
  int fr = lane & 15, fq = lane >> 4;      // frag row, k-block
  f32x4 acc[2][2];
#pragma unroll
  for (int i = 0; i < 2; ++i)
#pragma unroll
    for (int j = 0; j < 2; ++j) acc[i][j] = (f32x4){0.f, 0.f, 0.f, 0.f};

  for (int kt = 0; kt < K; kt += 32) {
    // ---- A tile: 64 rows x 32 k -> hi/lo bf16, 16B vector writes ----
    short8 vh, vl;
    if (CONV) {
      int m = m0 + sr;
      int b = m / 784, rm = m % 784, ho = rm / 28, wo = rm % 28;
      int k = kt + sq;                      // octet never straddles a tap (96 % 8 == 0)
      int k9 = k / 96, ci0 = k % 96;
      int hi = 2 * ho - 1 + k9 / 3, wi = 2 * wo - 1 + k9 % 3;
      if (hi >= 0 && hi < 56 && wi >= 0 && wi < 56) {
        const float* src = &A[((size_t)b * 3136 + hi * 56 + wi) * 96 + ci0];
        float4 a0 = *(const float4*)src;
        float4 a1 = *(const float4*)(src + 4);
        float av[8] = {a0.x, a0.y, a0.z, a0.w, a1.x, a1.y, a1.z, a1.w};
#pragma unroll
        for (int j = 0; j < 8; ++j) {
          unsigned short h = f2b(av[j]);
          vh[j] = (short)h;
          vl[j] = (short)f2b(av[j] - b2f16(h));
        }
      } else {
#pragma unroll
        for (int j = 0; j < 8; ++j) { vh[j] = 0; vl[j] = 0; }
      }
    } else {
      const float4 a0 = *(const float4*)&A[(size_t)(m0 + sr) * K + kt + sq];
      const float4 a1 = *(const float4*)&A[(size_t)(m0 + sr) * K + kt + sq + 4];
      float av[8] = {a0.x, a0.y, a0.z, a0.w, a1.x, a1.y, a1.z, a1.w};
#pragma unroll
      for (int j = 0; j < 8; ++j) {
        unsigned short h = f2b(av[j]);
        vh[j] = (short)h;
        vl[j] = (short)f2b(av[j] - b2f16(h));
      }
    }
    *(short8*)&AsH[sr][sq] = vh;
    *(short8*)&AsL[sr][sq] = vl;
    // ---- B tile ----
    {
      int n = n0 + sr;
      if (n < N) {
        *(short8*)&BsH[sr][sq] = *(const short8*)&WH[(size_t)n * K + kt + sq];
        *(short8*)&BsL[sr][sq] = *(const short8*)&WL[(size_t)n * K + kt + sq];
      } else {
        short8 z = {0, 0, 0, 0, 0, 0, 0, 0};
        *(short8*)&BsH[sr][sq] = z;
        *(short8*)&BsL[sr][sq] = z;
      }
    }
    __syncthreads();
    short8 ah[2], al[2], bh[2], bl[2];
#pragma unroll
    for (int s = 0; s < 2; ++s) {
      ah[s] = *(const short8*)&AsH[wm * 32 + s * 16 + fr][fq * 8];
      al[s] = *(const short8*)&AsL[wm * 32 + s * 16 + fr][fq * 8];
      bh[s] = *(const short8*)&BsH[wn * 32 + s * 16 + fr][fq * 8];
      bl[s] = *(const short8*)&BsL[wn * 32 + s * 16 + fr][fq * 8];
    }
#pragma unroll
    for (int i = 0; i < 2; ++i)
#pragma unroll
      for (int j = 0; j < 2; ++j) {
        acc[i][j] = __builtin_amdgcn_mfma_f32_16x16x32_bf16(ah[i], bh[j], acc[i][j], 0, 0, 0);
        acc[i][j] = __builtin_amdgcn_mfma_f32_16x16x32_bf16(ah[i], bl[j], acc[i][j], 0, 0, 0);
        acc[i][j] = __builtin_amdgcn_mfma_f32_16x16x32_bf16(al[i], bh[j], acc[i][j], 0, 0, 0);
      }
    __syncthreads();
  }
  // epilogue: C/D layout col = lane&15, row = (lane>>4)*4 + r   [m89]
#pragma unroll
  for (int i = 0; i < 2; ++i) {
#pragma unroll
    for (int j = 0; j < 2; ++j) {
      int n = n0 + wn * 32 + j * 16 + fr;
#pragma unroll
      for (int r = 0; r < 4; ++r) {
        int m = m0 + wm * 32 + i * 16 + fq * 4 + r;
        float v = acc[i][j][r];
        float pa = 0.f;
        if (EPI == 3) pa = __shfl_xor(v, 1);  // rope partner (n^1 <-> lane^1); all lanes
        if (n >= N) continue;
        if (bias) v += bias[n];
        if (EPI == 1) v = 0.5f * v * (1.f + erff(v * 0.70710678118654752f));
        if (EPI == 3) {
          // rope + scatter: n -> (sec, h, dh); m -> (b, mm)
          int sec = n / 192, d = n % 192, h = d / 32, dh = d % 32;
          int b = m / 784, mm = m % 784;
          float val;
          if (sec < 2) {
            int jj = dh >> 1;
            float cc = ct[mm * 16 + jj], ss = st[mm * 16 + jj];
            val = (dh & 1) ? (v * cc + pa * ss) : (v * cc - pa * ss);
          } else val = v;
          float* dst = (sec == 0) ? o1 : ((sec == 1) ? o2 : o3);
          dst[(((size_t)b * 6 + h) * 784 + mm) * 32 + dh] = val;
        } else if (EPI == 2) {
          C[(size_t)m * N + n] += v;
        } else {
          C[(size_t)m * N + n] = v;
        }
      }
      if (EPI == 4 && n < N) {
        // transposed store: 4 consecutive m at fixed n -> one float4
        int mb = m0 + wm * 32 + i * 16 + fq * 4;
        float4 tv = make_float4(acc[i][j][0], acc[i][j][1], acc[i][j][2], acc[i][j][3]);
        *(float4*)&o1[(size_t)n * M + mb] = tv;
      }
    }
  }
}

// ---------------- pass1: per-input softmax stats; kkT[96][25088] coalesced ----------------
__global__ void k_pass1(const float* __restrict__ kkT, const float* __restrict__ q,
    const float* __restrict__ rpb, const float* __restrict__ tau,
    float* __restrict__ M, float* __restrict__ Z) {
  int id = blockIdx.x * 256 + threadIdx.x;
  if (id >= 8 * 3136) return;
  int b = id / 3136, n = id % 3136;
  int r = n / 56, c = n % 56, r0 = r >> 1, c0 = c >> 1;
  int oi[9];
#pragma unroll
  for (int kki = 0; kki < 9; ++kki) {
    int dr = kki / 3 - 1, dc = kki % 3 - 1;
    int rr = min(max(r0 + dr, 0), 27), cc = min(max(c0 + dc, 0), 27);
    oi[kki] = rr * 28 + cc;
  }
  float scale = expf(tau[0]);
  float lg[9]; bool keep[9];
  float mx = -1e30f;
#pragma unroll
  for (int kki = 0; kki < 9; ++kki) {
    bool kp = true;
#pragma unroll
    for (int k2 = kki + 1; k2 < 9; ++k2) if (oi[k2] == oi[kki]) kp = false;
    keep[kki] = kp;
    if (kp) {
      const float* qr = q + ((size_t)b * 784 + oi[kki]) * 96;
      float d = 0.f;
      for (int i = 0; i < 96; ++i) d += kkT[(size_t)i * 25088 + id] * qr[i];
      lg[kki] = d * scale + rpb[kki];
      mx = fmaxf(mx, lg[kki]);
    } else lg[kki] = -1e30f;
  }
  float z = 0.f;
#pragma unroll
  for (int kki = 0; kki < 9; ++kki) if (keep[kki]) z += expf(lg[kki] - mx);
  M[id] = mx; Z[id] = z;
}

// ---------------- pass2: gather contributors, upd, /denom, LN, residual ----------------
__global__ __launch_bounds__(192) void k_pass2(const float* __restrict__ kk,
    const float* __restrict__ q, const float* __restrict__ vv,
    const float* __restrict__ M, const float* __restrict__ Z,
    const float* __restrict__ rpb, const float* __restrict__ tau,
    const float* __restrict__ g, const float* __restrict__ bb, float* __restrict__ xout) {
  int blk = blockIdx.x, b = blk / 784, m = blk % 784;
  int r2 = m / 28, c2 = m % 28;
  int r0lo = (r2 == 0) ? 0 : r2 - 1, r0hi = (r2 == 27) ? 27 : r2 + 1;
  int c0lo = (c2 == 0) ? 0 : c2 - 1, c0hi = (c2 == 27) ? 27 : c2 + 1;
  int nrow = 2 * (r0hi - r0lo + 1), ncol = 2 * (c0hi - c0lo + 1);
  int cnt = nrow * ncol;  // <= 36
  __shared__ float qm[96], p[36];
  __shared__ int nlist[36];
  __shared__ float2 red[192];
  int t = threadIdx.x;
  if (t < 96) qm[t] = q[(size_t)blk * 96 + t];
  __syncthreads();
  if (t < cnt) {
    int rr = 2 * r0lo + t / ncol, cc = 2 * c0lo + t % ncol;
    int n = rr * 56 + cc, rr0 = rr >> 1, cc0 = cc >> 1;
    int kkf = 0;
#pragma unroll
    for (int kki = 0; kki < 9; ++kki) {
      int dr = kki / 3 - 1, dc = kki % 3 - 1;
      int ra = min(max(rr0 + dr, 0), 27), ca = min(max(cc0 + dc, 0), 27);
      if (ra == r2 && ca == c2) kkf = kki;  // last-kk-wins (matches numpy overwrite)
    }
    const float* krow = kk + ((size_t)b * 3136 + n) * 96;
    float d = 0.f;
    for (int i = 0; i < 96; ++i) d += krow[i] * qm[i];
    float scale = expf(tau[0]);
    float lg = d * scale + rpb[kkf];
    size_t idn = (size_t)b * 3136 + n;
    p[t] = expf(lg - M[idn]) / Z[idn];
    nlist[t] = n;
  }
  __syncthreads();
  float denom = 0.f;
  for (int jn = 0; jn < cnt; ++jn) denom += p[jn];
  float acc = 0.f;
  for (int jn = 0; jn < cnt; ++jn)
    acc += p[jn] * vv[((size_t)b * 3136 + nlist[jn]) * 192 + t];
  float upd = acc / (denom + 1e-8f);
  red[t] = make_float2(upd, upd * upd);
  __syncthreads();
  for (int s = 128; s > 0; s >>= 1) {
    if (t < s && t + s < 192) { red[t].x += red[t + s].x; red[t].y += red[t + s].y; }
    __syncthreads();
  }
  float mean = red[0].x / 192.f, var = red[0].y / 192.f - mean * mean;
  float rstd = rsqrtf(var + 1e-5f);
  xout[(size_t)blk * 192 + t] += (upd - mean) * rstd * g[t] + bb[t];
}

// ---------------- neighborhood attention 7x7: wide, vectorized, split-PV ----------------
__global__ __launch_bounds__(256) void k_attn(const float* __restrict__ q3,
    const float* __restrict__ k3, const float* __restrict__ v3, float* __restrict__ ob) {
  int bid = blockIdx.x;
  int swz = (bid & 7) * 1176 + (bid >> 3);  // bijective on [0,9408)
  int unit = swz * 4 + (threadIdx.x >> 6);
  int l = threadIdx.x & 63;
  int b = unit / (6 * 784), rem = unit % (6 * 784), h = rem / 784, m = rem % 784;
  int i = m / 28, j = m % 28;
  int ib = min(max(i, 3), 24) - 3, jb = min(max(j, 3), 24) - 3;
  size_t base = (size_t)(b * 6 + h) * 784 * 32;
  const float4* q4 = (const float4*)(q3 + base + (size_t)m * 32);
  float4 qv[8];
#pragma unroll
  for (int e = 0; e < 8; ++e) qv[e] = q4[e];
  float logit = -1e30f;
  if (l < 49) {
    int nk = (ib + l / 7) * 28 + (jb + l % 7);
    const float4* k4 = (const float4*)(k3 + base + (size_t)nk * 32);
    float a = 0.f;
#pragma unroll
    for (int e = 0; e < 8; ++e) {
      float4 kv = k4[e];
      a += qv[e].x * kv.x + qv[e].y * kv.y + qv[e].z * kv.z + qv[e].w * kv.w;
    }
    logit = a * 0.17677669529663687f;  // 32^-0.5
  }
  float mx = logit;
  for (int off = 32; off; off >>= 1) mx = fmaxf(mx, __shfl_xor(mx, off));
  float p = (l < 49) ? expf(logit - mx) : 0.f;
  float sum = p;
  for (int off = 32; off; off >>= 1) sum += __shfl_xor(sum, off);
  int half = l >> 5, d = l & 31;
  int kbeg = half ? 25 : 0, kend = half ? 49 : 25;
  float acc = 0.f;
  for (int kki = kbeg; kki < kend; ++kki) {
    float pk = __shfl(p, kki);
    int nk = (ib + kki / 7) * 28 + (jb + kki % 7);
    acc += pk * v3[base + (size_t)nk * 32 + d];
  }
  acc += __shfl_xor(acc, 32);
  if (l < 32)
    ob[(((size_t)b * 784 + m) * 6 + h) * 32 + l] = acc / sum;
}

extern "C" void kernel_launch(void* const* d_in, const int* in_sizes, int n_in,
                              void* d_out, int out_size, void* d_ws, size_t ws_size,
                              hipStream_t stream) {
  (void)in_sizes; (void)n_in; (void)out_size; (void)ws_size;
  const float* x        = (const float*)d_in[0];
  const float* convw    = (const float*)d_in[1];
  const float* qw       = (const float*)d_in[2];
  const float* kw       = (const float*)d_in[3];
  const float* vw       = (const float*)d_in[4];
  const float* ln_in_g  = (const float*)d_in[5];
  const float* ln_in_b  = (const float*)d_in[6];
  const float* ln_out_g = (const float*)d_in[7];
  const float* ln_out_b = (const float*)d_in[8];
  const float* ln_at_g  = (const float*)d_in[9];
  const float* ln_at_b  = (const float*)d_in[10];
  const float* ln_ml_g  = (const float*)d_in[11];
  const float* ln_ml_b  = (const float*)d_in[12];
  const float* gw1      = (const float*)d_in[13];
  const float* gb1      = (const float*)d_in[14];
  const float* gw2      = (const float*)d_in[15];
  const float* gb2      = (const float*)d_in[16];
  const float* tau      = (const float*)d_in[17];
  const float* rpb      = (const float*)d_in[18];
  const float* bln1g    = (const float*)d_in[19];
  const float* bln1b    = (const float*)d_in[20];
  const float* bln2g    = (const float*)d_in[21];
  const float* bln2b    = (const float*)d_in[22];
  const float* bqkvw    = (const float*)d_in[23];
  const float* bprojw   = (const float*)d_in[24];
  const float* bprojb   = (const float*)d_in[25];
  const float* bmw1     = (const float*)d_in[26];
  const float* bmb1     = (const float*)d_in[27];
  const float* bmw2     = (const float*)d_in[28];
  const float* bmb2     = (const float*)d_in[29];

  float* XOUT = (float*)d_out;  // residual stream lives in d_out (f32, 8*784*192)

  float* W = (float*)d_ws;
  size_t off = 0;
  float* XN96  = W + off; off += (size_t)25088 * 96;
  float* XN192 = W + off; off += (size_t)6272 * 192;
  float* Kb    = W + off; off += (size_t)25088 * 96;
  float* KbT   = W + off; off += (size_t)25088 * 96;   // written by K-GEMM epilogue
  float* Vb    = W + off; off += (size_t)25088 * 192;
  float* Qb    = W + off; off += (size_t)6272 * 96;
  float* Mb    = W + off; off += (size_t)25088;
  float* Zb    = W + off; off += (size_t)25088;
  float* H1    = W + off; off += (size_t)6272 * 576;
  float* T2    = W + off; off += (size_t)6272 * 192;   // also CRAW
  float* CT    = W + off; off += (size_t)784 * 16;
  float* ST    = W + off; off += (size_t)784 * 16;
  short* WBH   = (short*)(W + off); off += (size_t)548352 + 16;  // hi arena
  short* WBL   = (short*)(W + off); off += (size_t)548352 + 16;  // lo arena
  const size_t O_c = 0, O_k = 165888, O_v = 175104, O_q = 193536,
               O_g1 = 211968, O_g2 = 285696, O_qkv = 359424, O_p = 580608,
               O_m1 = 654336, O_m2 = 875520;
  // aliases (group-phase buffers dead in block phase)
  float* CRAW = T2;
  float* Q3 = Kb;
  float* K3 = KbT;
  float* V3 = Vb;
  float* OB = Vb + (size_t)1204224;

  k_castw<<<4284, 256, 0, stream>>>(convw, kw, vw, qw, gw1, gw2, bqkvw, bprojw,
                                    bmw1, bmw2, WBH, WBL);
  k_rope<<<49, 256, 0, stream>>>(CT, ST);

  // conv (implicit GEMM, K=864, tap-major weights) + LN
  k_mgemm<0, 1><<<dim3(98, 3), 256, 0, stream>>>(x, WBH + O_c, WBL + O_c, nullptr,
      CRAW, 6272, 192, 864, nullptr, nullptr, nullptr, nullptr, nullptr);
  k_ln_epi<0><<<1568, 256, 0, stream>>>(CRAW, ln_out_g, ln_out_b, XOUT, 6272);

  // k,v projections; K-GEMM also emits KbT (EPI=4)
  k_ln<96><<<6272, 256, 0, stream>>>(x, ln_in_g, ln_in_b, XN96, 25088);
  k_mgemm<4, 0><<<dim3(392, 2), 256, 0, stream>>>(XN96, WBH + O_k, WBL + O_k, nullptr,
      Kb, 25088, 96, 96, nullptr, nullptr, KbT, nullptr, nullptr);
  k_mgemm<0, 0><<<dim3(392, 3), 256, 0, stream>>>(XN96, WBH + O_v, WBL + O_v, nullptr,
      Vb, 25088, 192, 96, nullptr, nullptr, nullptr, nullptr, nullptr);

  for (int it = 0; it < 3; ++it) {
    k_ln<192><<<1568, 256, 0, stream>>>(XOUT, ln_out_g, ln_out_b, XN192, 6272);
    k_mgemm<0, 0><<<dim3(98, 2), 256, 0, stream>>>(XN192, WBH + O_q, WBL + O_q, nullptr,
        Qb, 6272, 96, 192, nullptr, nullptr, nullptr, nullptr, nullptr);
    k_pass1<<<98, 256, 0, stream>>>(KbT, Qb, rpb, tau, Mb, Zb);
    k_pass2<<<6272, 192, 0, stream>>>(Kb, Qb, Vb, Mb, Zb, rpb, tau, ln_at_g, ln_at_b, XOUT);
    k_mgemm<1, 0><<<dim3(98, 6), 256, 0, stream>>>(XOUT, WBH + O_g1, WBL + O_g1, gb1,
        H1, 6272, 384, 192, nullptr, nullptr, nullptr, nullptr, nullptr);
    k_mgemm<0, 0><<<dim3(98, 3), 256, 0, stream>>>(H1, WBH + O_g2, WBL + O_g2, gb2,
        T2, 6272, 192, 384, nullptr, nullptr, nullptr, nullptr, nullptr);
    k_ln_epi<1><<<1568, 256, 0, stream>>>(T2, ln_ml_g, ln_ml_b, XOUT, 6272);
  }

  for (int i = 0; i < 2; ++i) {
    k_ln<192><<<1568, 256, 0, stream>>>(XOUT, bln1g + (size_t)i * 192,
                                        bln1b + (size_t)i * 192, XN192, 6272);
    // qkv GEMM with fused rope+scatter epilogue (EPI=3)
    k_mgemm<3, 0><<<dim3(98, 9), 256, 0, stream>>>(XN192, WBH + O_qkv + (size_t)i * 110592,
        WBL + O_qkv + (size_t)i * 110592, nullptr,
        nullptr, 6272, 576, 192, CT, ST, Q3, K3, V3);
    k_attn<<<9408, 256, 0, stream>>>(Q3, K3, V3, OB);
    k_mgemm<2, 0><<<dim3(98, 3), 256, 0, stream>>>(OB, WBH + O_p + (size_t)i * 36864,
        WBL + O_p + (size_t)i * 36864, bprojb + (size_t)i * 192,
        XOUT, 6272, 192, 192, nullptr, nullptr, nullptr, nullptr, nullptr);
    k_ln<192><<<1568, 256, 0, stream>>>(XOUT, bln2g + (size_t)i * 192,
                                        bln2b + (size_t)i * 192, XN192, 6272);
    k_mgemm<1, 0><<<dim3(98, 9), 256, 0, stream>>>(XN192, WBH + O_m1 + (size_t)i * 110592,
        WBL + O_m1 + (size_t)i * 110592, bmb1 + (size_t)i * 576,
        H1, 6272, 576, 192, nullptr, nullptr, nullptr, nullptr, nullptr);
    k_mgemm<2, 0><<<dim3(98, 3), 256, 0, stream>>>(H1, WBH + O_m2 + (size_t)i * 110592,
        WBL + O_m2 + (size_t)i * 110592, bmb2 + (size_t)i * 192,
        XOUT, 6272, 192, 576, nullptr, nullptr, nullptr, nullptr, nullptr);
  }
}